// Round 12
// baseline (491.789 us; speedup 1.0000x reference)
//
#include <hip/hip_runtime.h>
#include <hip/hip_bf16.h>

typedef unsigned short ushort_t;
typedef __attribute__((ext_vector_type(8))) short short8;
typedef __attribute__((ext_vector_type(4))) float float4v;

#define ATTN_BLOCKS 2048

__device__ __forceinline__ float bfu_lo(unsigned u) {
    return __uint_as_float(u << 16);
}
__device__ __forceinline__ float bfu_hi(unsigned u) {
    return __uint_as_float(u & 0xffff0000u);
}
__device__ __forceinline__ ushort_t f2bf(float f) {
    __hip_bfloat16 h = __float2bfloat16(f);
    return *reinterpret_cast<ushort_t*>(&h);
}

// Wall layout per layer: 30 col-tiles (466 cols used), tile = 1024 ushorts:
//   idx = ct*1024 + kch*512 + lane*8 + j
// cols: 0..127 q | 128..255 k | 256..383 v | 384..447 skip | 448..465 qc

// ---------------- fused setup ----------------

__global__ __launch_bounds__(256) void setup_kernel(
    const float* __restrict__ x, const float* __restrict__ node_W,
    const float* __restrict__ node_b,
    const float* __restrict__ edge_W, const float* __restrict__ edge_b,
    const float* __restrict__ We, const float* __restrict__ be,
    const float* __restrict__ Wq, const float* __restrict__ bq,
    const float* __restrict__ Wk, const float* __restrict__ bk,
    const float* __restrict__ Wv, const float* __restrict__ bv,
    const float* __restrict__ Wskip, const float* __restrict__ bskip,
    float* __restrict__ h, ushort_t* __restrict__ h_bf,
    int* __restrict__ counts,
    float* __restrict__ Wc, float* __restrict__ bcb,
    ushort_t* __restrict__ Wall_arr, float* __restrict__ Wall_bias,
    int O0, int O1, int O2, int N) {
    int b = blockIdx.x, t = threadIdx.x;
    if (b < O0) {
        int idx = b * 256 + t;
        if (idx < N * 64) {
            int n = idx >> 6, c = idx & 63;
            float acc = node_b[c];
#pragma unroll
            for (int j = 0; j < 16; ++j) acc += x[n * 16 + j] * node_W[j * 64 + c];
            h[idx] = acc;
            h_bf[idx] = f2bf(acc);
        }
    } else if (b < O1) {
        int i = (b - O0) * 256 + t;
        if (i < N) counts[i] = 0;
    } else if (b < O2) {
        int tid = (b - O1) * 256 + t;
        if (tid < 2048) {
            int l = tid >> 10, d = (tid >> 7) & 7, j = tid & 127;
            float s = 0.f;
            for (int m = 0; m < 64; ++m) s += edge_W[d * 64 + m] * We[l * 8192 + m * 128 + j];
            Wc[l * 1024 + d * 128 + j] = s;
        } else if (tid < 2048 + 256) {
            int u = tid - 2048;
            int l = u >> 7, j = u & 127;
            float s = be[l * 128 + j];
            for (int m = 0; m < 64; ++m) s += edge_b[m] * We[l * 8192 + m * 128 + j];
            bcb[l * 128 + j] = s;
        }
    } else {
        int tid = (b - O2) * 256 + t;
        if (tid < 2 * 28672) {
            int l = tid / 28672, u = tid % 28672;
            int j = u & 7, ln = (u >> 3) & 63, kch = (u >> 9) & 1, ct = u >> 10;
            int nn = ln & 15, quad = ln >> 4;
            int k = kch * 32 + quad * 8 + j;
            int col = ct * 16 + nn;
            float v;
            if (col < 128)      v = Wq[l * 8192 + k * 128 + col];
            else if (col < 256) v = Wk[l * 8192 + k * 128 + col - 128];
            else if (col < 384) v = Wv[l * 8192 + k * 128 + col - 256];
            else                v = Wskip[l * 4096 + k * 64 + col - 384];
            Wall_arr[(size_t)l * 32768 + ct * 1024 + kch * 512 + ln * 8 + j] = f2bf(v);
        } else if (tid < 2 * 28672 + 2 * 448) {
            int u = tid - 2 * 28672;
            int l = u / 448, col = u % 448;
            float v;
            if (col < 128)      v = bq[l * 128 + col];
            else if (col < 256) v = bk[l * 128 + col - 128];
            else if (col < 384) v = bv[l * 128 + col - 256];
            else                v = bskip[l * 64 + col - 384];
            Wall_bias[l * 512 + col] = v;
        }
    }
}

// combine2: qc composed weights into Wall fragments
__global__ void combine2_kernel(const float* __restrict__ Wq, const float* __restrict__ bq,
                                const float* __restrict__ Wc, const float* __restrict__ bcb,
                                ushort_t* __restrict__ Wall_arr, float* __restrict__ Wall_bias) {
    int tid = blockIdx.x * 256 + threadIdx.x;
    if (tid < 2304) {
        int l = tid / 1152, u = tid % 1152, k = u / 18, j = u % 18;
        float s = 0.f;
        if (j < 16) {
            int hh = j >> 3, d = j & 7;
            for (int c = 0; c < 64; ++c)
                s += Wq[l * 8192 + k * 128 + hh * 64 + c] * Wc[l * 1024 + d * 128 + hh * 64 + c];
        } else {
            int hh = j - 16;
            for (int c = 0; c < 64; ++c)
                s += Wq[l * 8192 + k * 128 + hh * 64 + c] * bcb[l * 128 + hh * 64 + c];
        }
        s *= 0.125f;
        int col = 448 + j;
        int ct = col >> 4, nn = col & 15;
        int kch = k >> 5, quad = (k >> 3) & 3, jj = k & 7;
        int ln = quad * 16 + nn;
        Wall_arr[(size_t)l * 32768 + ct * 1024 + kch * 512 + ln * 8 + jj] = f2bf(s);
    } else if (tid < 2304 + 36) {
        int u = tid - 2304;
        int l = u / 18, j = u % 18;
        float s = 0.f;
        if (j < 16) {
            int hh = j >> 3, d = j & 7;
            for (int c = 0; c < 64; ++c)
                s += bq[l * 128 + hh * 64 + c] * Wc[l * 1024 + d * 128 + hh * 64 + c];
        } else {
            int hh = j - 16;
            for (int c = 0; c < 64; ++c)
                s += bq[l * 128 + hh * 64 + c] * bcb[l * 128 + hh * 64 + c];
        }
        Wall_bias[l * 512 + 448 + j] = 0.125f * s;
    }
}

// ---------------- CSR build ----------------

__global__ void csr_count_kernel(const int* __restrict__ dst, int* __restrict__ counts, int E) {
    int e = blockIdx.x * 256 + threadIdx.x;
    if (e < E) atomicAdd(&counts[dst[e]], 1);
}

__global__ void scan1_kernel(const int* __restrict__ counts, int* __restrict__ rowptr,
                             int* __restrict__ bsums, int N) {
    __shared__ int s[256];
    int t = threadIdx.x, i = blockIdx.x * 256 + t;
    int v = (i < N) ? counts[i] : 0;
    s[t] = v;
    __syncthreads();
    for (int d = 1; d < 256; d <<= 1) {
        int x = (t >= d) ? s[t - d] : 0;
        __syncthreads();
        s[t] += x;
        __syncthreads();
    }
    if (i < N) rowptr[i] = s[t] - v;
    if (t == 255) bsums[blockIdx.x] = s[255];
}

// scan3 with scan2 folded in: every block redundantly block-scans bsums in LDS
__global__ void scan3_kernel(int* __restrict__ rowptr, const int* __restrict__ bsums,
                             int* __restrict__ cursor, int N, int E, int nb) {
    __shared__ int sh[256];
    int t = threadIdx.x;
    int v = (t < nb) ? bsums[t] : 0;
    sh[t] = v;
    __syncthreads();
    for (int d = 1; d < 256; d <<= 1) {
        int x = (t >= d) ? sh[t - d] : 0;
        __syncthreads();
        sh[t] += x;
        __syncthreads();
    }
    int blk = blockIdx.x;
    int offv = (blk == 0) ? 0 : sh[blk - 1];  // exclusive block offset
    int i = blk * 256 + t;
    if (i < N) {
        int r = rowptr[i] + offv;
        rowptr[i] = r;
        cursor[i] = r;
    }
    if (i == 0) rowptr[N] = E;
}

__global__ void csr_fill_kernel(const int* __restrict__ dst, const int* __restrict__ src,
                                const float* __restrict__ edge_attr, int* __restrict__ cursor,
                                int* __restrict__ csr_src, float* __restrict__ ea_perm, int E) {
    int e = blockIdx.x * 256 + threadIdx.x;
    if (e < E) {
        int pos = atomicAdd(&cursor[dst[e]], 1);
        csr_src[pos] = src[e] * 768 + 256;
        float4 a0 = *(const float4*)(edge_attr + (size_t)e * 8);
        float4 a1 = *(const float4*)(edge_attr + (size_t)e * 8 + 4);
        *(float4*)(ea_perm + (size_t)pos * 8) = a0;
        *(float4*)(ea_perm + (size_t)pos * 8 + 4) = a1;
    }
}

// ---------------- per-layer MFMA GEMM: [32 x 64] @ [64 x 466] ----------------

__global__ __launch_bounds__(256) void qkv_mfma_kernel(
    const ushort_t* __restrict__ h_bf,
    const ushort_t* __restrict__ Wall_arr, const float* __restrict__ Wall_bias,
    ushort_t* __restrict__ qkv, float* __restrict__ outbuf, float* __restrict__ qcbuf, int N) {
    int wave = threadIdx.x >> 6, lane = threadIdx.x & 63;
    int quad = lane >> 4, nn = lane & 15;
    int n0 = blockIdx.x * 32;
    int nodeA = n0 + nn;       if (nodeA >= N) nodeA = N - 1;
    int nodeB = n0 + 16 + nn;  if (nodeB >= N) nodeB = N - 1;
    const ushort_t* apA = h_bf + (size_t)nodeA * 64 + quad * 8;
    const ushort_t* apB = h_bf + (size_t)nodeB * 64 + quad * 8;
    short8 aA0 = *(const short8*)apA;
    short8 aA1 = *(const short8*)(apA + 32);
    short8 aB0 = *(const short8*)apB;
    short8 aB1 = *(const short8*)(apB + 32);
    int ct_start = (wave < 2) ? wave * 8 : (16 + (wave - 2) * 7);
    int ct_cnt = (wave < 2) ? 8 : 7;
    for (int i = 0; i < ct_cnt; ++i) {
        int ct = ct_start + i;
        const ushort_t* bp = Wall_arr + (size_t)ct * 1024 + lane * 8;
        short8 b0 = *(const short8*)bp;
        short8 b1 = *(const short8*)(bp + 512);
        float4v cA = {0.f, 0.f, 0.f, 0.f};
        float4v cB = {0.f, 0.f, 0.f, 0.f};
        cA = __builtin_amdgcn_mfma_f32_16x16x32_bf16(aA0, b0, cA, 0, 0, 0);
        cA = __builtin_amdgcn_mfma_f32_16x16x32_bf16(aA1, b1, cA, 0, 0, 0);
        cB = __builtin_amdgcn_mfma_f32_16x16x32_bf16(aB0, b0, cB, 0, 0, 0);
        cB = __builtin_amdgcn_mfma_f32_16x16x32_bf16(aB1, b1, cB, 0, 0, 0);
        int col = ct * 16 + nn;
        float bias = Wall_bias[col];
#pragma unroll
        for (int g = 0; g < 2; ++g) {
            float4v c = (g == 0) ? cA : cB;
            int nbase = n0 + g * 16 + quad * 4;
            if (col < 384) {
                int cm;
                if (col < 128) cm = col;
                else if (col < 256) { int cc = col - 128; cm = 128 + ((cc >> 1) << 2) + (cc & 1); }
                else { int cc = col - 256; cm = 128 + ((cc >> 1) << 2) + 2 + (cc & 1); }
                ushort_t* qp = qkv + (size_t)nbase * 384 + cm;
#pragma unroll
                for (int r = 0; r < 4; ++r)
                    if (nbase + r < N) qp[(size_t)r * 384] = f2bf(c[r] + bias);
            } else if (col < 448) {
                float* op = outbuf + (size_t)nbase * 64 + (col - 448 + 64);
#pragma unroll
                for (int r = 0; r < 4; ++r)
                    if (nbase + r < N) op[(size_t)r * 64] = c[r] + bias;
            } else if (col < 466) {
                float* qp2 = qcbuf + (size_t)nbase * 20 + (col - 448);
#pragma unroll
                for (int r = 0; r < 4; ++r)
                    if (nbase + r < N) qp2[(size_t)r * 20] = c[r] + bias;
            }
        }
    }
}

// ---------------- attention + fused BN partial stats ----------------

__global__ __launch_bounds__(256) void attn_kernel(
    const ushort_t* __restrict__ qkv, const float* __restrict__ qcbuf,
    const int* __restrict__ csr_src, const float* __restrict__ ea_perm,
    const int* __restrict__ rowptr,
    const float* __restrict__ Wc, const float* __restrict__ bcb,
    float* __restrict__ outbuf, float* __restrict__ part, int N) {
    __shared__ float Wc_s[1024];
    __shared__ float bc_s[128];
    __shared__ float sred[4][64];
    int t = threadIdx.x;
    for (int i = t; i < 1024; i += 256) Wc_s[i] = Wc[i];
    if (t < 128) bc_s[t] = bcb[t];
    __syncthreads();
    int lane = t & 63, wid = t >> 6;
    int half = lane >> 5, l31 = lane & 31;
    const char* qkvb = (const char*)qkv;
    float sa0 = 0.f, sa1 = 0.f, sq0 = 0.f, sq1 = 0.f;  // BN stats (half==0 lanes)
    for (int n = blockIdx.x * 4 + wid; n < N; n += gridDim.x * 4) {
        int start = rowptr[n], end = rowptr[n + 1];
        float2* op = (float2*)(outbuf + (size_t)n * 64 + 2 * l31);
        if (end <= start) {
            if (half == 0) {
                float2 cur = *op;   // outbuf holds skip
                sa0 += cur.x; sq0 += cur.x * cur.x;
                sa1 += cur.y; sq1 += cur.y * cur.y;
            }
            continue;
        }
        unsigned qraw = *(const unsigned*)(qkvb + (size_t)n * 768 + 4 * lane);
        float qx = bfu_lo(qraw), qy = bfu_hi(qraw);
        const float4 qcA = *(const float4*)(qcbuf + (size_t)n * 20 + half * 8);
        const float4 qcB = *(const float4*)(qcbuf + (size_t)n * 20 + half * 8 + 4);
        float qb = qcbuf[(size_t)n * 20 + 16 + half];
        float lsum = 0.f, ax = 0.f, ay = 0.f;
        float4 se0 = {0.f, 0.f, 0.f, 0.f}, se1 = {0.f, 0.f, 0.f, 0.f};
        for (int seg = start; seg < end; seg += 64) {
            int segcnt = min(64, end - seg);
            int li = (lane < segcnt) ? lane : (segcnt - 1);
            int offL = csr_src[seg + li];
            uint2 kvc[4], kvn[4];
#pragma unroll
            for (int j = 0; j < 4; ++j) {
                int idx = min(j, segcnt - 1);
                int o = __shfl(offL, idx);
                kvc[j] = *(const uint2*)(qkvb + (size_t)(unsigned)o + 8 * lane);
            }
            int base = 0;
            for (; base + 4 <= segcnt; base += 4) {
                if (base + 4 < segcnt) {
#pragma unroll
                    for (int j = 0; j < 4; ++j) {
                        int idx = min(base + 4 + j, segcnt - 1);
                        int o = __shfl(offL, idx);
                        kvn[j] = *(const uint2*)(qkvb + (size_t)(unsigned)o + 8 * lane);
                    }
                }
                // unmasked fast path
                float4 a0[4], a1[4];
                float dt[4];
#pragma unroll
                for (int j = 0; j < 4; ++j) {
                    const float* eap = ea_perm + (size_t)(seg + base + j) * 8;
                    a0[j] = *(const float4*)eap;
                    a1[j] = *(const float4*)(eap + 4);
                    dt[j] = qx * bfu_lo(kvc[j].x) + qy * bfu_hi(kvc[j].x);
                }
#pragma unroll
                for (int m = 1; m <= 16; m <<= 1) {
#pragma unroll
                    for (int j = 0; j < 4; ++j) dt[j] += __shfl_xor(dt[j], m);
                }
#pragma unroll
                for (int j = 0; j < 4; ++j) {
                    float s0 = dt[j] * 0.125f
                        + qcA.x * a0[j].x + qcA.y * a0[j].y + qcA.z * a0[j].z + qcA.w * a0[j].w
                        + qcB.x * a1[j].x + qcB.y * a1[j].y + qcB.z * a1[j].z + qcB.w * a1[j].w
                        + qb;
                    float p = __expf(fmaxf(s0, -60.f));
                    lsum += p;
                    ax += p * bfu_lo(kvc[j].y);
                    ay += p * bfu_hi(kvc[j].y);
                    se0.x += p * a0[j].x; se0.y += p * a0[j].y;
                    se0.z += p * a0[j].z; se0.w += p * a0[j].w;
                    se1.x += p * a1[j].x; se1.y += p * a1[j].y;
                    se1.z += p * a1[j].z; se1.w += p * a1[j].w;
                }
#pragma unroll
                for (int j = 0; j < 4; ++j) kvc[j] = kvn[j];
            }
            int rem = segcnt - base;
            if (rem) {
                // masked tail (kvc holds clamped-duplicated loads)
                float4 a0[4], a1[4];
                float dt[4];
#pragma unroll
                for (int j = 0; j < 4; ++j) {
                    int gi = seg + base + ((j < rem) ? j : 0);
                    const float* eap = ea_perm + (size_t)gi * 8;
                    a0[j] = *(const float4*)eap;
                    a1[j] = *(const float4*)(eap + 4);
                    dt[j] = qx * bfu_lo(kvc[j].x) + qy * bfu_hi(kvc[j].x);
                }
#pragma unroll
                for (int m = 1; m <= 16; m <<= 1) {
#pragma unroll
                    for (int j = 0; j < 4; ++j) dt[j] += __shfl_xor(dt[j], m);
                }
#pragma unroll
                for (int j = 0; j < 4; ++j) {
                    float s0 = dt[j] * 0.125f
                        + qcA.x * a0[j].x + qcA.y * a0[j].y + qcA.z * a0[j].z + qcA.w * a0[j].w
                        + qcB.x * a1[j].x + qcB.y * a1[j].y + qcB.z * a1[j].z + qcB.w * a1[j].w
                        + qb;
                    float p = (j < rem) ? __expf(fmaxf(s0, -60.f)) : 0.f;
                    lsum += p;
                    ax += p * bfu_lo(kvc[j].y);
                    ay += p * bfu_hi(kvc[j].y);
                    se0.x += p * a0[j].x; se0.y += p * a0[j].y;
                    se0.z += p * a0[j].z; se0.w += p * a0[j].w;
                    se1.x += p * a1[j].x; se1.y += p * a1[j].y;
                    se1.z += p * a1[j].z; se1.w += p * a1[j].w;
                }
            }
        }
        int j0 = half * 64 + 2 * l31;
        float w0 = lsum * bc_s[j0], w1 = lsum * bc_s[j0 + 1];
        w0 += se0.x * Wc_s[0 * 128 + j0] + se0.y * Wc_s[1 * 128 + j0] +
              se0.z * Wc_s[2 * 128 + j0] + se0.w * Wc_s[3 * 128 + j0] +
              se1.x * Wc_s[4 * 128 + j0] + se1.y * Wc_s[5 * 128 + j0] +
              se1.z * Wc_s[6 * 128 + j0] + se1.w * Wc_s[7 * 128 + j0];
        w1 += se0.x * Wc_s[0 * 128 + j0 + 1] + se0.y * Wc_s[1 * 128 + j0 + 1] +
              se0.z * Wc_s[2 * 128 + j0 + 1] + se0.w * Wc_s[3 * 128 + j0 + 1] +
              se1.x * Wc_s[4 * 128 + j0 + 1] + se1.y * Wc_s[5 * 128 + j0 + 1] +
              se1.z * Wc_s[6 * 128 + j0 + 1] + se1.w * Wc_s[7 * 128 + j0 + 1];
        float inv = 1.f / lsum;
        float ox = (ax + w0) * inv, oy = (ay + w1) * inv;
        float px = __shfl_xor(ox, 32), py = __shfl_xor(oy, 32);
        ox = 0.5f * (ox + px);
        oy = 0.5f * (oy + py);
        if (half == 0) {
            float2 cur = *op;
            float fx = cur.x + ox, fy = cur.y + oy;
            *op = make_float2(fx, fy);
            sa0 += fx; sq0 += fx * fx;
            sa1 += fy; sq1 += fy * fy;
        }
    }
    __syncthreads();
    if (half == 0) { sred[wid][2 * l31] = sa0; sred[wid][2 * l31 + 1] = sa1; }
    __syncthreads();
    if (t < 64) part[(size_t)blockIdx.x * 128 + t] =
        sred[0][t] + sred[1][t] + sred[2][t] + sred[3][t];
    __syncthreads();
    if (half == 0) { sred[wid][2 * l31] = sq0; sred[wid][2 * l31 + 1] = sq1; }
    __syncthreads();
    if (t < 64) part[(size_t)blockIdx.x * 128 + 64 + t] =
        sred[0][t] + sred[1][t] + sred[2][t] + sred[3][t];
}

// ---------------- BN reduce + apply ----------------

__global__ __launch_bounds__(256) void bnreduce_kernel(const float* __restrict__ part,
                                                       float* __restrict__ bnsums) {
    int s = blockIdx.x;  // 0..127
    int t = threadIdx.x;
    float a = 0.f;
    for (int b = t; b < ATTN_BLOCKS; b += 256) a += part[(size_t)b * 128 + s];
    __shared__ float sh[256];
    sh[t] = a;
    __syncthreads();
    for (int d = 128; d; d >>= 1) {
        if (t < d) sh[t] += sh[t + d];
        __syncthreads();
    }
    if (t == 0) bnsums[s] = sh[0];
}

__global__ __launch_bounds__(256) void bnapply_kernel(
    const float* __restrict__ outbuf, const float* __restrict__ bnsums,
    const float* __restrict__ gamma, const float* __restrict__ beta,
    const float* __restrict__ gate_W, const float* __restrict__ gate_b,
    float* __restrict__ h, ushort_t* __restrict__ h_bf,
    float* __restrict__ gatebuf, int do_pool, int N) {
    int idx = blockIdx.x * 256 + threadIdx.x;
    if (idx >= N * 64) return;
    int c = idx & 63, n = idx >> 6;
    float invN = 1.f / (float)N;
    float mean = bnsums[c] * invN;
    float var = bnsums[64 + c] * invN - mean * mean;
    float scale = gamma[c] * rsqrtf(var + 1e-5f);
    float shift = beta[c] - mean * scale;
    float o = outbuf[idx] * scale + shift;
    o = (o > 0.f) ? o : 0.01f * o;
    float hn = h[idx] + o;
    h[idx] = hn;
    h_bf[idx] = f2bf(hn);
    if (do_pool) {
        float g = hn * gate_W[c];
#pragma unroll
        for (int off = 32; off; off >>= 1) g += __shfl_xor(g, off);
        if (c == 0) gatebuf[n] = g + gate_b[0];
    }
}

// ---------------- pooling ----------------

__global__ __launch_bounds__(256) void pool_max_kernel(const float* __restrict__ gatebuf,
                                                       const int* __restrict__ batch,
                                                       float* __restrict__ m, int N) {
    int b = blockIdx.x;
    int lo = 0, hi = N;
    while (lo < hi) { int mid = (lo + hi) >> 1; if (batch[mid] < b) lo = mid + 1; else hi = mid; }
    int start = lo;
    lo = start; hi = N;
    while (lo < hi) { int mid = (lo + hi) >> 1; if (batch[mid] <= b) lo = mid + 1; else hi = mid; }
    int end = lo;
    int t = threadIdx.x, lane = t & 63, wid = t >> 6;
    __shared__ float sm[4];
    float mx = -1e30f;
    for (int n = start + t; n < end; n += 256) mx = fmaxf(mx, gatebuf[n]);
#pragma unroll
    for (int off = 32; off; off >>= 1) mx = fmaxf(mx, __shfl_xor(mx, off));
    if (lane == 0) sm[wid] = mx;
    __syncthreads();
    if (t == 0) m[b] = fmaxf(fmaxf(sm[0], sm[1]), fmaxf(sm[2], sm[3]));
}

__global__ __launch_bounds__(256) void pool_acc_kernel(
    const float* __restrict__ h, const float* __restrict__ gatebuf,
    const int* __restrict__ batch, const float* __restrict__ gmax,
    float* __restrict__ pacc, float* __restrict__ pden, int N) {
    int b = blockIdx.x >> 3, chunk = blockIdx.x & 7;
    int lo = 0, hi = N;
    while (lo < hi) { int mid = (lo + hi) >> 1; if (batch[mid] < b) lo = mid + 1; else hi = mid; }
    int start = lo;
    lo = start; hi = N;
    while (lo < hi) { int mid = (lo + hi) >> 1; if (batch[mid] <= b) lo = mid + 1; else hi = mid; }
    int end = lo;
    int lane = threadIdx.x & 63, wid = threadIdx.x >> 6;
    int gwid = chunk * 4 + wid;
    float mb = gmax[b];
    float acc = 0.f, den = 0.f;
    for (int n = start + gwid; n < end; n += 32) {
        float ge = __expf(gatebuf[n] - mb);
        acc += ge * h[(size_t)n * 64 + lane];
        den += ge;
    }
    __shared__ float sacc[4][64];
    __shared__ float sden[4];
    sacc[wid][lane] = acc;
    if (lane == 0) sden[wid] = den;
    __syncthreads();
    if (wid == 0) {
        pacc[(size_t)blockIdx.x * 64 + lane] =
            sacc[0][lane] + sacc[1][lane] + sacc[2][lane] + sacc[3][lane];
        if (lane == 0) pden[blockIdx.x] = sden[0] + sden[1] + sden[2] + sden[3];
    }
}

__global__ void pool_fin_kernel(const float* __restrict__ pacc, const float* __restrict__ pden,
                                const float* __restrict__ out_W, const float* __restrict__ out_b,
                                float* __restrict__ out) {
    int b = blockIdx.x, c = threadIdx.x;
    float pc = 0.f, dv = 0.f;
#pragma unroll
    for (int j = 0; j < 8; ++j) {
        pc += pacc[(size_t)(b * 8 + j) * 64 + c];
        dv += pden[b * 8 + j];
    }
    float s = pc * out_W[c];
#pragma unroll
    for (int off = 32; off; off >>= 1) s += __shfl_xor(s, off);
    if (c == 0) {
        if (dv <= 0.f) dv = 1.f;
        float v = s / dv + out_b[0];
        out[b] = 1.f / (1.f + __expf(-v));
    }
}

// ---------------- host ----------------

extern "C" void kernel_launch(void* const* d_in, const int* in_sizes, int n_in,
                              void* d_out, int out_size, void* d_ws, size_t ws_size,
                              hipStream_t stream) {
    const float* x         = (const float*)d_in[0];
    const float* edge_attr = (const float*)d_in[1];
    const int*   edge_src  = (const int*)d_in[2];
    const int*   edge_dst  = (const int*)d_in[3];
    const int*   batch     = (const int*)d_in[4];
    const float* node_W    = (const float*)d_in[5];
    const float* node_b    = (const float*)d_in[6];
    const float* edge_W    = (const float*)d_in[7];
    const float* edge_b    = (const float*)d_in[8];
    const float* Wq        = (const float*)d_in[9];
    const float* bq        = (const float*)d_in[10];
    const float* Wk        = (const float*)d_in[11];
    const float* bk        = (const float*)d_in[12];
    const float* Wv        = (const float*)d_in[13];
    const float* bv        = (const float*)d_in[14];
    const float* We        = (const float*)d_in[15];
    const float* be        = (const float*)d_in[16];
    const float* Wskip     = (const float*)d_in[17];
    const float* bskip     = (const float*)d_in[18];
    const float* gamma     = (const float*)d_in[19];
    const float* beta      = (const float*)d_in[20];
    const float* gate_W    = (const float*)d_in[21];
    const float* gate_b    = (const float*)d_in[22];
    const float* out_W     = (const float*)d_in[23];
    const float* out_b     = (const float*)d_in[24];
    float* out = (float*)d_out;

    const int N = in_sizes[0] / 16;
    const int E = in_sizes[2];

    char* ws = (char*)d_ws;
    size_t off = 0;
    auto alloc = [&](size_t bytes) {
        size_t o = off;
        off += (bytes + 255) & ~(size_t)255;
        return o;
    };
    float*    h        = (float*)(ws + alloc((size_t)N * 64 * 4));
    ushort_t* h_bf     = (ushort_t*)(ws + alloc((size_t)N * 64 * 2));
    ushort_t* qkv      = (ushort_t*)(ws + alloc((size_t)N * 384 * 2));
    float*    outbuf   = (float*)(ws + alloc((size_t)N * 64 * 4));
    float*    qcbuf    = (float*)(ws + alloc((size_t)N * 20 * 4));
    int*      rowptr   = (int*)(ws + alloc((size_t)(N + 1) * 4));
    int*      cursor   = (int*)(ws + alloc((size_t)N * 4));
    int*      counts   = (int*)(ws + alloc((size_t)N * 4));
    int*      bsums    = (int*)(ws + alloc(1024));
    int*      csr_src  = (int*)(ws + alloc((size_t)E * 4));
    float*    ea_perm  = (float*)(ws + alloc((size_t)E * 8 * 4));
    float*    Wc       = (float*)(ws + alloc(2 * 1024 * 4));
    float*    bcb      = (float*)(ws + alloc(2 * 128 * 4));
    ushort_t* Wall_arr = (ushort_t*)(ws + alloc(2 * 32768 * 2));
    float*    Wall_b   = (float*)(ws + alloc(2 * 512 * 4));
    float*    bnsums   = (float*)(ws + alloc(128 * 4));
    float*    gatebuf  = (float*)(ws + alloc((size_t)N * 4));
    float*    gmax     = (float*)(ws + alloc(64 * 4));
    float*    pacc     = (float*)(ws + alloc((size_t)ATTN_BLOCKS * 128 * 4));
    float*    pden     = (float*)(ws + alloc(512 * 4));
    if (off > ws_size) return;

    int O0 = (N * 64 + 255) / 256;
    int O1 = O0 + (N + 255) / 256;
    int O2 = O1 + 9;
    int O3 = O2 + 228;
    setup_kernel<<<O3, 256, 0, stream>>>(
        x, node_W, node_b, edge_W, edge_b, We, be, Wq, bq, Wk, bk, Wv, bv, Wskip, bskip,
        h, h_bf, counts, Wc, bcb, Wall_arr, Wall_b, O0, O1, O2, N);
    combine2_kernel<<<10, 256, 0, stream>>>(Wq, bq, Wc, bcb, Wall_arr, Wall_b);

    csr_count_kernel<<<(E + 255) / 256, 256, 0, stream>>>(edge_dst, counts, E);
    int nb = (N + 255) / 256;
    scan1_kernel<<<nb, 256, 0, stream>>>(counts, rowptr, bsums, N);
    scan3_kernel<<<nb, 256, 0, stream>>>(rowptr, bsums, cursor, N, E, nb);
    csr_fill_kernel<<<(E + 255) / 256, 256, 0, stream>>>(edge_dst, edge_src, edge_attr,
                                                         cursor, csr_src, ea_perm, E);

    for (int l = 0; l < 2; ++l) {
        qkv_mfma_kernel<<<(N + 31) / 32, 256, 0, stream>>>(
            h_bf, Wall_arr + (size_t)l * 32768, Wall_b + l * 512, qkv, outbuf, qcbuf, N);
        attn_kernel<<<ATTN_BLOCKS, 256, 0, stream>>>(qkv, qcbuf, csr_src, ea_perm,
                                                     rowptr, Wc + l * 1024,
                                                     bcb + l * 128, outbuf, pacc, N);
        bnreduce_kernel<<<128, 256, 0, stream>>>(pacc, bnsums);
        bnapply_kernel<<<(N * 64 + 255) / 256, 256, 0, stream>>>(
            outbuf, bnsums, gamma + l * 64, beta + l * 64, gate_W, gate_b,
            h, h_bf, gatebuf, (l == 1) ? 1 : 0, N);
    }

    pool_max_kernel<<<64, 256, 0, stream>>>(gatebuf, batch, gmax, N);
    pool_acc_kernel<<<512, 256, 0, stream>>>(h, gatebuf, batch, gmax, pacc, pden, N);
    pool_fin_kernel<<<64, 64, 0, stream>>>(pacc, pden, out_W, out_b, out);
}

// Round 13
// 464.408 us; speedup vs baseline: 1.0590x; 1.0590x over previous
//
#include <hip/hip_runtime.h>
#include <hip/hip_bf16.h>

typedef unsigned short ushort_t;
typedef __attribute__((ext_vector_type(8))) short short8;
typedef __attribute__((ext_vector_type(4))) float float4v;

#define ATTN_BLOCKS 2048

__device__ __forceinline__ float bfu_lo(unsigned u) {
    return __uint_as_float(u << 16);
}
__device__ __forceinline__ float bfu_hi(unsigned u) {
    return __uint_as_float(u & 0xffff0000u);
}
__device__ __forceinline__ ushort_t f2bf(float f) {
    __hip_bfloat16 h = __float2bfloat16(f);
    return *reinterpret_cast<ushort_t*>(&h);
}

// Wall layout per layer: 30 col-tiles (466 cols used), tile = 1024 ushorts:
//   idx = ct*1024 + kch*512 + lane*8 + j
// cols: 0..127 q | 128..255 k | 256..383 v | 384..447 skip | 448..465 qc

// ---------------- fused setup ----------------

__global__ __launch_bounds__(256) void setup_kernel(
    const float* __restrict__ x, const float* __restrict__ node_W,
    const float* __restrict__ node_b,
    const float* __restrict__ edge_W, const float* __restrict__ edge_b,
    const float* __restrict__ We, const float* __restrict__ be,
    const float* __restrict__ Wq, const float* __restrict__ bq,
    const float* __restrict__ Wk, const float* __restrict__ bk,
    const float* __restrict__ Wv, const float* __restrict__ bv,
    const float* __restrict__ Wskip, const float* __restrict__ bskip,
    float* __restrict__ h, ushort_t* __restrict__ h_bf,
    int* __restrict__ counts,
    float* __restrict__ Wc, float* __restrict__ bcb,
    ushort_t* __restrict__ Wall_arr, float* __restrict__ Wall_bias,
    int O0, int O1, int O2, int N) {
    int b = blockIdx.x, t = threadIdx.x;
    if (b < O0) {
        int idx = b * 256 + t;
        if (idx < N * 64) {
            int n = idx >> 6, c = idx & 63;
            float acc = node_b[c];
#pragma unroll
            for (int j = 0; j < 16; ++j) acc += x[n * 16 + j] * node_W[j * 64 + c];
            h[idx] = acc;
            h_bf[idx] = f2bf(acc);
        }
    } else if (b < O1) {
        int i = (b - O0) * 256 + t;
        if (i < N) counts[i] = 0;
    } else if (b < O2) {
        int tid = (b - O1) * 256 + t;
        if (tid < 2048) {
            int l = tid >> 10, d = (tid >> 7) & 7, j = tid & 127;
            float s = 0.f;
            for (int m = 0; m < 64; ++m) s += edge_W[d * 64 + m] * We[l * 8192 + m * 128 + j];
            Wc[l * 1024 + d * 128 + j] = s;
        } else if (tid < 2048 + 256) {
            int u = tid - 2048;
            int l = u >> 7, j = u & 127;
            float s = be[l * 128 + j];
            for (int m = 0; m < 64; ++m) s += edge_b[m] * We[l * 8192 + m * 128 + j];
            bcb[l * 128 + j] = s;
        }
    } else {
        int tid = (b - O2) * 256 + t;
        if (tid < 2 * 28672) {
            int l = tid / 28672, u = tid % 28672;
            int j = u & 7, ln = (u >> 3) & 63, kch = (u >> 9) & 1, ct = u >> 10;
            int nn = ln & 15, quad = ln >> 4;
            int k = kch * 32 + quad * 8 + j;
            int col = ct * 16 + nn;
            float v;
            if (col < 128)      v = Wq[l * 8192 + k * 128 + col];
            else if (col < 256) v = Wk[l * 8192 + k * 128 + col - 128];
            else if (col < 384) v = Wv[l * 8192 + k * 128 + col - 256];
            else                v = Wskip[l * 4096 + k * 64 + col - 384];
            Wall_arr[(size_t)l * 32768 + ct * 1024 + kch * 512 + ln * 8 + j] = f2bf(v);
        } else if (tid < 2 * 28672 + 2 * 448) {
            int u = tid - 2 * 28672;
            int l = u / 448, col = u % 448;
            float v;
            if (col < 128)      v = bq[l * 128 + col];
            else if (col < 256) v = bk[l * 128 + col - 128];
            else if (col < 384) v = bv[l * 128 + col - 256];
            else                v = bskip[l * 64 + col - 384];
            Wall_bias[l * 512 + col] = v;
        }
    }
}

// combine2: qc composed weights into Wall fragments
__global__ void combine2_kernel(const float* __restrict__ Wq, const float* __restrict__ bq,
                                const float* __restrict__ Wc, const float* __restrict__ bcb,
                                ushort_t* __restrict__ Wall_arr, float* __restrict__ Wall_bias) {
    int tid = blockIdx.x * 256 + threadIdx.x;
    if (tid < 2304) {
        int l = tid / 1152, u = tid % 1152, k = u / 18, j = u % 18;
        float s = 0.f;
        if (j < 16) {
            int hh = j >> 3, d = j & 7;
            for (int c = 0; c < 64; ++c)
                s += Wq[l * 8192 + k * 128 + hh * 64 + c] * Wc[l * 1024 + d * 128 + hh * 64 + c];
        } else {
            int hh = j - 16;
            for (int c = 0; c < 64; ++c)
                s += Wq[l * 8192 + k * 128 + hh * 64 + c] * bcb[l * 128 + hh * 64 + c];
        }
        s *= 0.125f;
        int col = 448 + j;
        int ct = col >> 4, nn = col & 15;
        int kch = k >> 5, quad = (k >> 3) & 3, jj = k & 7;
        int ln = quad * 16 + nn;
        Wall_arr[(size_t)l * 32768 + ct * 1024 + kch * 512 + ln * 8 + jj] = f2bf(s);
    } else if (tid < 2304 + 36) {
        int u = tid - 2304;
        int l = u / 18, j = u % 18;
        float s = 0.f;
        if (j < 16) {
            int hh = j >> 3, d = j & 7;
            for (int c = 0; c < 64; ++c)
                s += bq[l * 128 + hh * 64 + c] * Wc[l * 1024 + d * 128 + hh * 64 + c];
        } else {
            int hh = j - 16;
            for (int c = 0; c < 64; ++c)
                s += bq[l * 128 + hh * 64 + c] * bcb[l * 128 + hh * 64 + c];
        }
        Wall_bias[l * 512 + 448 + j] = 0.125f * s;
    }
}

// ---------------- CSR build ----------------

__global__ void csr_count_kernel(const int* __restrict__ dst, int* __restrict__ counts, int E) {
    int e = blockIdx.x * 256 + threadIdx.x;
    if (e < E) atomicAdd(&counts[dst[e]], 1);
}

__global__ void scan1_kernel(const int* __restrict__ counts, int* __restrict__ rowptr,
                             int* __restrict__ bsums, int N) {
    __shared__ int s[256];
    int t = threadIdx.x, i = blockIdx.x * 256 + t;
    int v = (i < N) ? counts[i] : 0;
    s[t] = v;
    __syncthreads();
    for (int d = 1; d < 256; d <<= 1) {
        int x = (t >= d) ? s[t - d] : 0;
        __syncthreads();
        s[t] += x;
        __syncthreads();
    }
    if (i < N) rowptr[i] = s[t] - v;
    if (t == 255) bsums[blockIdx.x] = s[255];
}

// scan3 with scan2 folded in: every block redundantly block-scans bsums in LDS
__global__ void scan3_kernel(int* __restrict__ rowptr, const int* __restrict__ bsums,
                             int* __restrict__ cursor, int N, int E, int nb) {
    __shared__ int sh[256];
    int t = threadIdx.x;
    int v = (t < nb) ? bsums[t] : 0;
    sh[t] = v;
    __syncthreads();
    for (int d = 1; d < 256; d <<= 1) {
        int x = (t >= d) ? sh[t - d] : 0;
        __syncthreads();
        sh[t] += x;
        __syncthreads();
    }
    int blk = blockIdx.x;
    int offv = (blk == 0) ? 0 : sh[blk - 1];  // exclusive block offset
    int i = blk * 256 + t;
    if (i < N) {
        int r = rowptr[i] + offv;
        rowptr[i] = r;
        cursor[i] = r;
    }
    if (i == 0) rowptr[N] = E;
}

__global__ void csr_fill_kernel(const int* __restrict__ dst, const int* __restrict__ src,
                                const float* __restrict__ edge_attr, int* __restrict__ cursor,
                                int* __restrict__ csr_src, float* __restrict__ ea_perm, int E) {
    int e = blockIdx.x * 256 + threadIdx.x;
    if (e < E) {
        int pos = atomicAdd(&cursor[dst[e]], 1);
        csr_src[pos] = src[e] * 768 + 256;
        float4 a0 = *(const float4*)(edge_attr + (size_t)e * 8);
        float4 a1 = *(const float4*)(edge_attr + (size_t)e * 8 + 4);
        *(float4*)(ea_perm + (size_t)pos * 8) = a0;
        *(float4*)(ea_perm + (size_t)pos * 8 + 4) = a1;
    }
}

// ---------------- per-layer MFMA GEMM: [32 x 64] @ [64 x 466] ----------------

__global__ __launch_bounds__(256) void qkv_mfma_kernel(
    const ushort_t* __restrict__ h_bf,
    const ushort_t* __restrict__ Wall_arr, const float* __restrict__ Wall_bias,
    ushort_t* __restrict__ qkv, float* __restrict__ outbuf, float* __restrict__ qcbuf, int N) {
    int wave = threadIdx.x >> 6, lane = threadIdx.x & 63;
    int quad = lane >> 4, nn = lane & 15;
    int n0 = blockIdx.x * 32;
    int nodeA = n0 + nn;       if (nodeA >= N) nodeA = N - 1;
    int nodeB = n0 + 16 + nn;  if (nodeB >= N) nodeB = N - 1;
    const ushort_t* apA = h_bf + (size_t)nodeA * 64 + quad * 8;
    const ushort_t* apB = h_bf + (size_t)nodeB * 64 + quad * 8;
    short8 aA0 = *(const short8*)apA;
    short8 aA1 = *(const short8*)(apA + 32);
    short8 aB0 = *(const short8*)apB;
    short8 aB1 = *(const short8*)(apB + 32);
    int ct_start = (wave < 2) ? wave * 8 : (16 + (wave - 2) * 7);
    int ct_cnt = (wave < 2) ? 8 : 7;
    for (int i = 0; i < ct_cnt; ++i) {
        int ct = ct_start + i;
        const ushort_t* bp = Wall_arr + (size_t)ct * 1024 + lane * 8;
        short8 b0 = *(const short8*)bp;
        short8 b1 = *(const short8*)(bp + 512);
        float4v cA = {0.f, 0.f, 0.f, 0.f};
        float4v cB = {0.f, 0.f, 0.f, 0.f};
        cA = __builtin_amdgcn_mfma_f32_16x16x32_bf16(aA0, b0, cA, 0, 0, 0);
        cA = __builtin_amdgcn_mfma_f32_16x16x32_bf16(aA1, b1, cA, 0, 0, 0);
        cB = __builtin_amdgcn_mfma_f32_16x16x32_bf16(aB0, b0, cB, 0, 0, 0);
        cB = __builtin_amdgcn_mfma_f32_16x16x32_bf16(aB1, b1, cB, 0, 0, 0);
        int col = ct * 16 + nn;
        float bias = Wall_bias[col];
#pragma unroll
        for (int g = 0; g < 2; ++g) {
            float4v c = (g == 0) ? cA : cB;
            int nbase = n0 + g * 16 + quad * 4;
            if (col < 384) {
                int cm;
                if (col < 128) cm = col;
                else if (col < 256) { int cc = col - 128; cm = 128 + ((cc >> 1) << 2) + (cc & 1); }
                else { int cc = col - 256; cm = 128 + ((cc >> 1) << 2) + 2 + (cc & 1); }
                ushort_t* qp = qkv + (size_t)nbase * 384 + cm;
#pragma unroll
                for (int r = 0; r < 4; ++r)
                    if (nbase + r < N) qp[(size_t)r * 384] = f2bf(c[r] + bias);
            } else if (col < 448) {
                float* op = outbuf + (size_t)nbase * 64 + (col - 448 + 64);
#pragma unroll
                for (int r = 0; r < 4; ++r)
                    if (nbase + r < N) op[(size_t)r * 64] = c[r] + bias;
            } else if (col < 466) {
                float* qp2 = qcbuf + (size_t)nbase * 20 + (col - 448);
#pragma unroll
                for (int r = 0; r < 4; ++r)
                    if (nbase + r < N) qp2[(size_t)r * 20] = c[r] + bias;
            }
        }
    }
}

// ---------------- attention + fused BN partial stats (R11 inner loop) ----------------

__global__ __launch_bounds__(256) void attn_kernel(
    const ushort_t* __restrict__ qkv, const float* __restrict__ qcbuf,
    const int* __restrict__ csr_src, const float* __restrict__ ea_perm,
    const int* __restrict__ rowptr,
    const float* __restrict__ Wc, const float* __restrict__ bcb,
    float* __restrict__ outbuf, float* __restrict__ part, int N) {
    __shared__ float Wc_s[1024];
    __shared__ float bc_s[128];
    __shared__ float sred[4][64];
    int t = threadIdx.x;
    for (int i = t; i < 1024; i += 256) Wc_s[i] = Wc[i];
    if (t < 128) bc_s[t] = bcb[t];
    __syncthreads();
    int lane = t & 63, wid = t >> 6;
    int half = lane >> 5, l31 = lane & 31;
    const char* qkvb = (const char*)qkv;
    float sa0 = 0.f, sa1 = 0.f, sq0 = 0.f, sq1 = 0.f;  // BN stats (half==0 lanes)
    for (int n = blockIdx.x * 4 + wid; n < N; n += gridDim.x * 4) {
        int start = rowptr[n], end = rowptr[n + 1];
        float2* op = (float2*)(outbuf + (size_t)n * 64 + 2 * l31);
        if (end <= start) {
            if (half == 0) {
                float2 cur = *op;   // outbuf holds skip
                sa0 += cur.x; sq0 += cur.x * cur.x;
                sa1 += cur.y; sq1 += cur.y * cur.y;
            }
            continue;
        }
        unsigned qraw = *(const unsigned*)(qkvb + (size_t)n * 768 + 4 * lane);
        float qx = bfu_lo(qraw), qy = bfu_hi(qraw);
        const float4 qcA = *(const float4*)(qcbuf + (size_t)n * 20 + half * 8);
        const float4 qcB = *(const float4*)(qcbuf + (size_t)n * 20 + half * 8 + 4);
        float qb = qcbuf[(size_t)n * 20 + 16 + half];
        float lsum = 0.f, ax = 0.f, ay = 0.f;
        float4 se0 = {0.f, 0.f, 0.f, 0.f}, se1 = {0.f, 0.f, 0.f, 0.f};
        for (int seg = start; seg < end; seg += 64) {
            int segcnt = min(64, end - seg);
            int li = (lane < segcnt) ? lane : (segcnt - 1);
            int offL = csr_src[seg + li];
            uint2 kvc[4], kvn[4];
#pragma unroll
            for (int j = 0; j < 4; ++j) {
                int idx = (j < segcnt) ? j : (segcnt - 1);
                int o = __shfl(offL, idx);
                kvc[j] = *(const uint2*)(qkvb + (size_t)(unsigned)o + 8 * lane);
            }
            for (int base = 0; base < segcnt; base += 4) {
                int nb2 = base + 4;
                if (nb2 < segcnt) {
#pragma unroll
                    for (int j = 0; j < 4; ++j) {
                        int idx = (nb2 + j < segcnt) ? (nb2 + j) : (segcnt - 1);
                        int o = __shfl(offL, idx);
                        kvn[j] = *(const uint2*)(qkvb + (size_t)(unsigned)o + 8 * lane);
                    }
                }
                float4 a0[4], a1[4];
                float dt[4];
#pragma unroll
                for (int j = 0; j < 4; ++j) {
                    int gi = seg + base + ((base + j < segcnt) ? j : 0);
                    const float* eap = ea_perm + (size_t)gi * 8;
                    a0[j] = *(const float4*)eap;
                    a1[j] = *(const float4*)(eap + 4);
                    dt[j] = qx * bfu_lo(kvc[j].x) + qy * bfu_hi(kvc[j].x);
                }
#pragma unroll
                for (int m = 1; m <= 16; m <<= 1) {
#pragma unroll
                    for (int j = 0; j < 4; ++j) dt[j] += __shfl_xor(dt[j], m);
                }
#pragma unroll
                for (int j = 0; j < 4; ++j) {
                    float s0 = dt[j] * 0.125f
                        + qcA.x * a0[j].x + qcA.y * a0[j].y + qcA.z * a0[j].z + qcA.w * a0[j].w
                        + qcB.x * a1[j].x + qcB.y * a1[j].y + qcB.z * a1[j].z + qcB.w * a1[j].w
                        + qb;
                    float p = (base + j < segcnt) ? __expf(fmaxf(s0, -60.f)) : 0.f;
                    lsum += p;
                    ax += p * bfu_lo(kvc[j].y);
                    ay += p * bfu_hi(kvc[j].y);
                    se0.x += p * a0[j].x; se0.y += p * a0[j].y;
                    se0.z += p * a0[j].z; se0.w += p * a0[j].w;
                    se1.x += p * a1[j].x; se1.y += p * a1[j].y;
                    se1.z += p * a1[j].z; se1.w += p * a1[j].w;
                }
#pragma unroll
                for (int j = 0; j < 4; ++j) kvc[j] = kvn[j];
            }
        }
        int j0 = half * 64 + 2 * l31;
        float w0 = lsum * bc_s[j0], w1 = lsum * bc_s[j0 + 1];
        w0 += se0.x * Wc_s[0 * 128 + j0] + se0.y * Wc_s[1 * 128 + j0] +
              se0.z * Wc_s[2 * 128 + j0] + se0.w * Wc_s[3 * 128 + j0] +
              se1.x * Wc_s[4 * 128 + j0] + se1.y * Wc_s[5 * 128 + j0] +
              se1.z * Wc_s[6 * 128 + j0] + se1.w * Wc_s[7 * 128 + j0];
        w1 += se0.x * Wc_s[0 * 128 + j0 + 1] + se0.y * Wc_s[1 * 128 + j0 + 1] +
              se0.z * Wc_s[2 * 128 + j0 + 1] + se0.w * Wc_s[3 * 128 + j0 + 1] +
              se1.x * Wc_s[4 * 128 + j0 + 1] + se1.y * Wc_s[5 * 128 + j0 + 1] +
              se1.z * Wc_s[6 * 128 + j0 + 1] + se1.w * Wc_s[7 * 128 + j0 + 1];
        float inv = 1.f / lsum;
        float ox = (ax + w0) * inv, oy = (ay + w1) * inv;
        float px = __shfl_xor(ox, 32), py = __shfl_xor(oy, 32);
        ox = 0.5f * (ox + px);
        oy = 0.5f * (oy + py);
        if (half == 0) {
            float2 cur = *op;
            float fx = cur.x + ox, fy = cur.y + oy;
            *op = make_float2(fx, fy);
            sa0 += fx; sq0 += fx * fx;
            sa1 += fy; sq1 += fy * fy;
        }
    }
    __syncthreads();
    if (half == 0) { sred[wid][2 * l31] = sa0; sred[wid][2 * l31 + 1] = sa1; }
    __syncthreads();
    if (t < 64) part[(size_t)blockIdx.x * 128 + t] =
        sred[0][t] + sred[1][t] + sred[2][t] + sred[3][t];
    __syncthreads();
    if (half == 0) { sred[wid][2 * l31] = sq0; sred[wid][2 * l31 + 1] = sq1; }
    __syncthreads();
    if (t < 64) part[(size_t)blockIdx.x * 128 + 64 + t] =
        sred[0][t] + sred[1][t] + sred[2][t] + sred[3][t];
}

// ---------------- BN reduce + apply ----------------

__global__ __launch_bounds__(256) void bnreduce_kernel(const float* __restrict__ part,
                                                       float* __restrict__ bnsums) {
    int s = blockIdx.x;  // 0..127
    int t = threadIdx.x;
    float a = 0.f;
    for (int b = t; b < ATTN_BLOCKS; b += 256) a += part[(size_t)b * 128 + s];
    __shared__ float sh[256];
    sh[t] = a;
    __syncthreads();
    for (int d = 128; d; d >>= 1) {
        if (t < d) sh[t] += sh[t + d];
        __syncthreads();
    }
    if (t == 0) bnsums[s] = sh[0];
}

__global__ __launch_bounds__(256) void bnapply_kernel(
    const float* __restrict__ outbuf, const float* __restrict__ bnsums,
    const float* __restrict__ gamma, const float* __restrict__ beta,
    const float* __restrict__ gate_W, const float* __restrict__ gate_b,
    float* __restrict__ h, ushort_t* __restrict__ h_bf,
    float* __restrict__ gatebuf, int do_pool, int N) {
    int idx = blockIdx.x * 256 + threadIdx.x;
    if (idx >= N * 64) return;
    int c = idx & 63, n = idx >> 6;
    float invN = 1.f / (float)N;
    float mean = bnsums[c] * invN;
    float var = bnsums[64 + c] * invN - mean * mean;
    float scale = gamma[c] * rsqrtf(var + 1e-5f);
    float shift = beta[c] - mean * scale;
    float o = outbuf[idx] * scale + shift;
    o = (o > 0.f) ? o : 0.01f * o;
    float hn = h[idx] + o;
    h[idx] = hn;
    h_bf[idx] = f2bf(hn);
    if (do_pool) {
        float g = hn * gate_W[c];
#pragma unroll
        for (int off = 32; off; off >>= 1) g += __shfl_xor(g, off);
        if (c == 0) gatebuf[n] = g + gate_b[0];
    }
}

// ---------------- pooling ----------------

__global__ __launch_bounds__(256) void pool_max_kernel(const float* __restrict__ gatebuf,
                                                       const int* __restrict__ batch,
                                                       float* __restrict__ m, int N) {
    int b = blockIdx.x;
    int lo = 0, hi = N;
    while (lo < hi) { int mid = (lo + hi) >> 1; if (batch[mid] < b) lo = mid + 1; else hi = mid; }
    int start = lo;
    lo = start; hi = N;
    while (lo < hi) { int mid = (lo + hi) >> 1; if (batch[mid] <= b) lo = mid + 1; else hi = mid; }
    int end = lo;
    int t = threadIdx.x, lane = t & 63, wid = t >> 6;
    __shared__ float sm[4];
    float mx = -1e30f;
    for (int n = start + t; n < end; n += 256) mx = fmaxf(mx, gatebuf[n]);
#pragma unroll
    for (int off = 32; off; off >>= 1) mx = fmaxf(mx, __shfl_xor(mx, off));
    if (lane == 0) sm[wid] = mx;
    __syncthreads();
    if (t == 0) m[b] = fmaxf(fmaxf(sm[0], sm[1]), fmaxf(sm[2], sm[3]));
}

__global__ __launch_bounds__(256) void pool_acc_kernel(
    const float* __restrict__ h, const float* __restrict__ gatebuf,
    const int* __restrict__ batch, const float* __restrict__ gmax,
    float* __restrict__ pacc, float* __restrict__ pden, int N) {
    int b = blockIdx.x >> 3, chunk = blockIdx.x & 7;
    int lo = 0, hi = N;
    while (lo < hi) { int mid = (lo + hi) >> 1; if (batch[mid] < b) lo = mid + 1; else hi = mid; }
    int start = lo;
    lo = start; hi = N;
    while (lo < hi) { int mid = (lo + hi) >> 1; if (batch[mid] <= b) lo = mid + 1; else hi = mid; }
    int end = lo;
    int lane = threadIdx.x & 63, wid = threadIdx.x >> 6;
    int gwid = chunk * 4 + wid;
    float mb = gmax[b];
    float acc = 0.f, den = 0.f;
    for (int n = start + gwid; n < end; n += 32) {
        float ge = __expf(gatebuf[n] - mb);
        acc += ge * h[(size_t)n * 64 + lane];
        den += ge;
    }
    __shared__ float sacc[4][64];
    __shared__ float sden[4];
    sacc[wid][lane] = acc;
    if (lane == 0) sden[wid] = den;
    __syncthreads();
    if (wid == 0) {
        pacc[(size_t)blockIdx.x * 64 + lane] =
            sacc[0][lane] + sacc[1][lane] + sacc[2][lane] + sacc[3][lane];
        if (lane == 0) pden[blockIdx.x] = sden[0] + sden[1] + sden[2] + sden[3];
    }
}

__global__ void pool_fin_kernel(const float* __restrict__ pacc, const float* __restrict__ pden,
                                const float* __restrict__ out_W, const float* __restrict__ out_b,
                                float* __restrict__ out) {
    int b = blockIdx.x, c = threadIdx.x;
    float pc = 0.f, dv = 0.f;
#pragma unroll
    for (int j = 0; j < 8; ++j) {
        pc += pacc[(size_t)(b * 8 + j) * 64 + c];
        dv += pden[b * 8 + j];
    }
    float s = pc * out_W[c];
#pragma unroll
    for (int off = 32; off; off >>= 1) s += __shfl_xor(s, off);
    if (c == 0) {
        if (dv <= 0.f) dv = 1.f;
        float v = s / dv + out_b[0];
        out[b] = 1.f / (1.f + __expf(-v));
    }
}

// ---------------- host ----------------

extern "C" void kernel_launch(void* const* d_in, const int* in_sizes, int n_in,
                              void* d_out, int out_size, void* d_ws, size_t ws_size,
                              hipStream_t stream) {
    const float* x         = (const float*)d_in[0];
    const float* edge_attr = (const float*)d_in[1];
    const int*   edge_src  = (const int*)d_in[2];
    const int*   edge_dst  = (const int*)d_in[3];
    const int*   batch     = (const int*)d_in[4];
    const float* node_W    = (const float*)d_in[5];
    const float* node_b    = (const float*)d_in[6];
    const float* edge_W    = (const float*)d_in[7];
    const float* edge_b    = (const float*)d_in[8];
    const float* Wq        = (const float*)d_in[9];
    const float* bq        = (const float*)d_in[10];
    const float* Wk        = (const float*)d_in[11];
    const float* bk        = (const float*)d_in[12];
    const float* Wv        = (const float*)d_in[13];
    const float* bv        = (const float*)d_in[14];
    const float* We        = (const float*)d_in[15];
    const float* be        = (const float*)d_in[16];
    const float* Wskip     = (const float*)d_in[17];
    const float* bskip     = (const float*)d_in[18];
    const float* gamma     = (const float*)d_in[19];
    const float* beta      = (const float*)d_in[20];
    const float* gate_W    = (const float*)d_in[21];
    const float* gate_b    = (const float*)d_in[22];
    const float* out_W     = (const float*)d_in[23];
    const float* out_b     = (const float*)d_in[24];
    float* out = (float*)d_out;

    const int N = in_sizes[0] / 16;
    const int E = in_sizes[2];

    char* ws = (char*)d_ws;
    size_t off = 0;
    auto alloc = [&](size_t bytes) {
        size_t o = off;
        off += (bytes + 255) & ~(size_t)255;
        return o;
    };
    float*    h        = (float*)(ws + alloc((size_t)N * 64 * 4));
    ushort_t* h_bf     = (ushort_t*)(ws + alloc((size_t)N * 64 * 2));
    ushort_t* qkv      = (ushort_t*)(ws + alloc((size_t)N * 384 * 2));
    float*    outbuf   = (float*)(ws + alloc((size_t)N * 64 * 4));
    float*    qcbuf    = (float*)(ws + alloc((size_t)N * 20 * 4));
    int*      rowptr   = (int*)(ws + alloc((size_t)(N + 1) * 4));
    int*      cursor   = (int*)(ws + alloc((size_t)N * 4));
    int*      counts   = (int*)(ws + alloc((size_t)N * 4));
    int*      bsums    = (int*)(ws + alloc(1024));
    int*      csr_src  = (int*)(ws + alloc((size_t)E * 4));
    float*    ea_perm  = (float*)(ws + alloc((size_t)E * 8 * 4));
    float*    Wc       = (float*)(ws + alloc(2 * 1024 * 4));
    float*    bcb      = (float*)(ws + alloc(2 * 128 * 4));
    ushort_t* Wall_arr = (ushort_t*)(ws + alloc(2 * 32768 * 2));
    float*    Wall_b   = (float*)(ws + alloc(2 * 512 * 4));
    float*    bnsums   = (float*)(ws + alloc(128 * 4));
    float*    gatebuf  = (float*)(ws + alloc((size_t)N * 4));
    float*    gmax     = (float*)(ws + alloc(64 * 4));
    float*    pacc     = (float*)(ws + alloc((size_t)ATTN_BLOCKS * 128 * 4));
    float*    pden     = (float*)(ws + alloc(512 * 4));
    if (off > ws_size) return;

    int O0 = (N * 64 + 255) / 256;
    int O1 = O0 + (N + 255) / 256;
    int O2 = O1 + 9;
    int O3 = O2 + 228;
    setup_kernel<<<O3, 256, 0, stream>>>(
        x, node_W, node_b, edge_W, edge_b, We, be, Wq, bq, Wk, bk, Wv, bv, Wskip, bskip,
        h, h_bf, counts, Wc, bcb, Wall_arr, Wall_b, O0, O1, O2, N);
    combine2_kernel<<<10, 256, 0, stream>>>(Wq, bq, Wc, bcb, Wall_arr, Wall_b);

    csr_count_kernel<<<(E + 255) / 256, 256, 0, stream>>>(edge_dst, counts, E);
    int nb = (N + 255) / 256;
    scan1_kernel<<<nb, 256, 0, stream>>>(counts, rowptr, bsums, N);
    scan3_kernel<<<nb, 256, 0, stream>>>(rowptr, bsums, cursor, N, E, nb);
    csr_fill_kernel<<<(E + 255) / 256, 256, 0, stream>>>(edge_dst, edge_src, edge_attr,
                                                         cursor, csr_src, ea_perm, E);

    for (int l = 0; l < 2; ++l) {
        qkv_mfma_kernel<<<(N + 31) / 32, 256, 0, stream>>>(
            h_bf, Wall_arr + (size_t)l * 32768, Wall_b + l * 512, qkv, outbuf, qcbuf, N);
        attn_kernel<<<ATTN_BLOCKS, 256, 0, stream>>>(qkv, qcbuf, csr_src, ea_perm,
                                                     rowptr, Wc + l * 1024,
                                                     bcb + l * 128, outbuf, pacc, N);
        bnreduce_kernel<<<128, 256, 0, stream>>>(pacc, bnsums);
        bnapply_kernel<<<(N * 64 + 255) / 256, 256, 0, stream>>>(
            outbuf, bnsums, gamma + l * 64, beta + l * 64, gate_W, gate_b,
            h, h_bf, gatebuf, (l == 1) ? 1 : 0, N);
    }

    pool_max_kernel<<<64, 256, 0, stream>>>(gatebuf, batch, gmax, N);
    pool_acc_kernel<<<512, 256, 0, stream>>>(h, gatebuf, batch, gmax, pacc, pden, N);
    pool_fin_kernel<<<64, 64, 0, stream>>>(pacc, pden, out_W, out_b, out);
}

// Round 14
// 442.142 us; speedup vs baseline: 1.1123x; 1.0504x over previous
//
#include <hip/hip_runtime.h>
#include <hip/hip_bf16.h>

typedef unsigned short ushort_t;
typedef __attribute__((ext_vector_type(8))) short short8;
typedef __attribute__((ext_vector_type(4))) float float4v;

#define ATTN_BLOCKS 2048

__device__ __forceinline__ float bfu_lo(unsigned u) {
    return __uint_as_float(u << 16);
}
__device__ __forceinline__ float bfu_hi(unsigned u) {
    return __uint_as_float(u & 0xffff0000u);
}
__device__ __forceinline__ ushort_t f2bf(float f) {
    __hip_bfloat16 h = __float2bfloat16(f);
    return *reinterpret_cast<ushort_t*>(&h);
}

// Wall layout per layer: 30 col-tiles (466 cols used), tile = 1024 ushorts:
//   idx = ct*1024 + kch*512 + lane*8 + j
// cols: 0..127 q | 128..255 k | 256..383 v | 384..447 skip | 448..465 qc

// ---------------- fused setup ----------------

__global__ __launch_bounds__(256) void setup_kernel(
    const float* __restrict__ x, const float* __restrict__ node_W,
    const float* __restrict__ node_b,
    const float* __restrict__ edge_W, const float* __restrict__ edge_b,
    const float* __restrict__ We, const float* __restrict__ be,
    const float* __restrict__ Wq, const float* __restrict__ bq,
    const float* __restrict__ Wk, const float* __restrict__ bk,
    const float* __restrict__ Wv, const float* __restrict__ bv,
    const float* __restrict__ Wskip, const float* __restrict__ bskip,
    float* __restrict__ h, ushort_t* __restrict__ h_bf,
    int* __restrict__ counts,
    float* __restrict__ Wc, float* __restrict__ bcb,
    ushort_t* __restrict__ Wall_arr, float* __restrict__ Wall_bias,
    int O0, int O1, int O2, int N) {
    int b = blockIdx.x, t = threadIdx.x;
    if (b < O0) {
        int idx = b * 256 + t;
        if (idx < N * 64) {
            int n = idx >> 6, c = idx & 63;
            float acc = node_b[c];
#pragma unroll
            for (int j = 0; j < 16; ++j) acc += x[n * 16 + j] * node_W[j * 64 + c];
            h[idx] = acc;
            h_bf[idx] = f2bf(acc);
        }
    } else if (b < O1) {
        int i = (b - O0) * 256 + t;
        if (i < N) counts[i] = 0;
    } else if (b < O2) {
        int tid = (b - O1) * 256 + t;
        if (tid < 2048) {
            int l = tid >> 10, d = (tid >> 7) & 7, j = tid & 127;
            float s = 0.f;
            for (int m = 0; m < 64; ++m) s += edge_W[d * 64 + m] * We[l * 8192 + m * 128 + j];
            Wc[l * 1024 + d * 128 + j] = s;
        } else if (tid < 2048 + 256) {
            int u = tid - 2048;
            int l = u >> 7, j = u & 127;
            float s = be[l * 128 + j];
            for (int m = 0; m < 64; ++m) s += edge_b[m] * We[l * 8192 + m * 128 + j];
            bcb[l * 128 + j] = s;
        }
    } else {
        int tid = (b - O2) * 256 + t;
        if (tid < 2 * 28672) {
            int l = tid / 28672, u = tid % 28672;
            int j = u & 7, ln = (u >> 3) & 63, kch = (u >> 9) & 1, ct = u >> 10;
            int nn = ln & 15, quad = ln >> 4;
            int k = kch * 32 + quad * 8 + j;
            int col = ct * 16 + nn;
            float v;
            if (col < 128)      v = Wq[l * 8192 + k * 128 + col];
            else if (col < 256) v = Wk[l * 8192 + k * 128 + col - 128];
            else if (col < 384) v = Wv[l * 8192 + k * 128 + col - 256];
            else                v = Wskip[l * 4096 + k * 64 + col - 384];
            Wall_arr[(size_t)l * 32768 + ct * 1024 + kch * 512 + ln * 8 + j] = f2bf(v);
        } else if (tid < 2 * 28672 + 2 * 448) {
            int u = tid - 2 * 28672;
            int l = u / 448, col = u % 448;
            float v;
            if (col < 128)      v = bq[l * 128 + col];
            else if (col < 256) v = bk[l * 128 + col - 128];
            else if (col < 384) v = bv[l * 128 + col - 256];
            else                v = bskip[l * 64 + col - 384];
            Wall_bias[l * 512 + col] = v;
        }
    }
}

// combine2: qc composed weights into Wall fragments
__global__ void combine2_kernel(const float* __restrict__ Wq, const float* __restrict__ bq,
                                const float* __restrict__ Wc, const float* __restrict__ bcb,
                                ushort_t* __restrict__ Wall_arr, float* __restrict__ Wall_bias) {
    int tid = blockIdx.x * 256 + threadIdx.x;
    if (tid < 2304) {
        int l = tid / 1152, u = tid % 1152, k = u / 18, j = u % 18;
        float s = 0.f;
        if (j < 16) {
            int hh = j >> 3, d = j & 7;
            for (int c = 0; c < 64; ++c)
                s += Wq[l * 8192 + k * 128 + hh * 64 + c] * Wc[l * 1024 + d * 128 + hh * 64 + c];
        } else {
            int hh = j - 16;
            for (int c = 0; c < 64; ++c)
                s += Wq[l * 8192 + k * 128 + hh * 64 + c] * bcb[l * 128 + hh * 64 + c];
        }
        s *= 0.125f;
        int col = 448 + j;
        int ct = col >> 4, nn = col & 15;
        int kch = k >> 5, quad = (k >> 3) & 3, jj = k & 7;
        int ln = quad * 16 + nn;
        Wall_arr[(size_t)l * 32768 + ct * 1024 + kch * 512 + ln * 8 + jj] = f2bf(s);
    } else if (tid < 2304 + 36) {
        int u = tid - 2304;
        int l = u / 18, j = u % 18;
        float s = 0.f;
        if (j < 16) {
            int hh = j >> 3, d = j & 7;
            for (int c = 0; c < 64; ++c)
                s += bq[l * 128 + hh * 64 + c] * Wc[l * 1024 + d * 128 + hh * 64 + c];
        } else {
            int hh = j - 16;
            for (int c = 0; c < 64; ++c)
                s += bq[l * 128 + hh * 64 + c] * bcb[l * 128 + hh * 64 + c];
        }
        Wall_bias[l * 512 + 448 + j] = 0.125f * s;
    }
}

// ---------------- CSR build ----------------

__global__ void csr_count_kernel(const int* __restrict__ dst, int* __restrict__ counts, int E) {
    int e = blockIdx.x * 256 + threadIdx.x;
    if (e < E) atomicAdd(&counts[dst[e]], 1);
}

__global__ void scan1_kernel(const int* __restrict__ counts, int* __restrict__ rowptr,
                             int* __restrict__ bsums, int N) {
    __shared__ int s[256];
    int t = threadIdx.x, i = blockIdx.x * 256 + t;
    int v = (i < N) ? counts[i] : 0;
    s[t] = v;
    __syncthreads();
    for (int d = 1; d < 256; d <<= 1) {
        int x = (t >= d) ? s[t - d] : 0;
        __syncthreads();
        s[t] += x;
        __syncthreads();
    }
    if (i < N) rowptr[i] = s[t] - v;
    if (t == 255) bsums[blockIdx.x] = s[255];
}

// scan3 with scan2 folded in
__global__ void scan3_kernel(int* __restrict__ rowptr, const int* __restrict__ bsums,
                             int* __restrict__ cursor, int N, int E, int nb) {
    __shared__ int sh[256];
    int t = threadIdx.x;
    int v = (t < nb) ? bsums[t] : 0;
    sh[t] = v;
    __syncthreads();
    for (int d = 1; d < 256; d <<= 1) {
        int x = (t >= d) ? sh[t - d] : 0;
        __syncthreads();
        sh[t] += x;
        __syncthreads();
    }
    int blk = blockIdx.x;
    int offv = (blk == 0) ? 0 : sh[blk - 1];
    int i = blk * 256 + t;
    if (i < N) {
        int r = rowptr[i] + offv;
        rowptr[i] = r;
        cursor[i] = r;
    }
    if (i == 0) rowptr[N] = E;
}

__global__ void csr_fill_kernel(const int* __restrict__ dst, const int* __restrict__ src,
                                const float* __restrict__ edge_attr, int* __restrict__ cursor,
                                int* __restrict__ csr_src, float* __restrict__ ea_perm, int E) {
    int e = blockIdx.x * 256 + threadIdx.x;
    if (e < E) {
        int pos = atomicAdd(&cursor[dst[e]], 1);
        csr_src[pos] = src[e] * 768 + 256;
        float4 a0 = *(const float4*)(edge_attr + (size_t)e * 8);
        float4 a1 = *(const float4*)(edge_attr + (size_t)e * 8 + 4);
        *(float4*)(ea_perm + (size_t)pos * 8) = a0;
        *(float4*)(ea_perm + (size_t)pos * 8 + 4) = a1;
    }
}

// ---------------- per-layer MFMA GEMM: [32 x 64] @ [64 x 466] (from global h_bf) ----

__global__ __launch_bounds__(256) void qkv_mfma_kernel(
    const ushort_t* __restrict__ h_bf,
    const ushort_t* __restrict__ Wall_arr, const float* __restrict__ Wall_bias,
    ushort_t* __restrict__ qkv, float* __restrict__ outbuf, float* __restrict__ qcbuf, int N) {
    int wave = threadIdx.x >> 6, lane = threadIdx.x & 63;
    int quad = lane >> 4, nn = lane & 15;
    int n0 = blockIdx.x * 32;
    int nodeA = n0 + nn;       if (nodeA >= N) nodeA = N - 1;
    int nodeB = n0 + 16 + nn;  if (nodeB >= N) nodeB = N - 1;
    const ushort_t* apA = h_bf + (size_t)nodeA * 64 + quad * 8;
    const ushort_t* apB = h_bf + (size_t)nodeB * 64 + quad * 8;
    short8 aA0 = *(const short8*)apA;
    short8 aA1 = *(const short8*)(apA + 32);
    short8 aB0 = *(const short8*)apB;
    short8 aB1 = *(const short8*)(apB + 32);
    int ct_start = (wave < 2) ? wave * 8 : (16 + (wave - 2) * 7);
    int ct_cnt = (wave < 2) ? 8 : 7;
    for (int i = 0; i < ct_cnt; ++i) {
        int ct = ct_start + i;
        const ushort_t* bp = Wall_arr + (size_t)ct * 1024 + lane * 8;
        short8 b0 = *(const short8*)bp;
        short8 b1 = *(const short8*)(bp + 512);
        float4v cA = {0.f, 0.f, 0.f, 0.f};
        float4v cB = {0.f, 0.f, 0.f, 0.f};
        cA = __builtin_amdgcn_mfma_f32_16x16x32_bf16(aA0, b0, cA, 0, 0, 0);
        cA = __builtin_amdgcn_mfma_f32_16x16x32_bf16(aA1, b1, cA, 0, 0, 0);
        cB = __builtin_amdgcn_mfma_f32_16x16x32_bf16(aB0, b0, cB, 0, 0, 0);
        cB = __builtin_amdgcn_mfma_f32_16x16x32_bf16(aB1, b1, cB, 0, 0, 0);
        int col = ct * 16 + nn;
        float bias = Wall_bias[col];
#pragma unroll
        for (int g = 0; g < 2; ++g) {
            float4v c = (g == 0) ? cA : cB;
            int nbase = n0 + g * 16 + quad * 4;
            if (col < 384) {
                int cm;
                if (col < 128) cm = col;
                else if (col < 256) { int cc = col - 128; cm = 128 + ((cc >> 1) << 2) + (cc & 1); }
                else { int cc = col - 256; cm = 128 + ((cc >> 1) << 2) + 2 + (cc & 1); }
                ushort_t* qp = qkv + (size_t)nbase * 384 + cm;
#pragma unroll
                for (int r = 0; r < 4; ++r)
                    if (nbase + r < N) qp[(size_t)r * 384] = f2bf(c[r] + bias);
            } else if (col < 448) {
                float* op = outbuf + (size_t)nbase * 64 + (col - 448 + 64);
#pragma unroll
                for (int r = 0; r < 4; ++r)
                    if (nbase + r < N) op[(size_t)r * 64] = c[r] + bias;
            } else if (col < 466) {
                float* qp2 = qcbuf + (size_t)nbase * 20 + (col - 448);
#pragma unroll
                for (int r = 0; r < 4; ++r)
                    if (nbase + r < N) qp2[(size_t)r * 20] = c[r] + bias;
            }
        }
    }
}

// ---------------- fused BN-apply(l) + qkv-MFMA(l+1): 32 nodes/block ----------------

__global__ __launch_bounds__(256) void bnqkv_kernel(
    const float* __restrict__ outbuf_in, const float* __restrict__ bnsums,
    const float* __restrict__ gamma, const float* __restrict__ beta,
    float* __restrict__ h,
    const ushort_t* __restrict__ Wall_arr, const float* __restrict__ Wall_bias,
    ushort_t* __restrict__ qkv, float* __restrict__ outbuf, float* __restrict__ qcbuf, int N) {
    __shared__ ushort_t hb[32 * 64];
    __shared__ float ss_scale[64], ss_shift[64];
    int t = threadIdx.x;
    if (t < 64) {
        float invN = 1.f / (float)N;
        float mean = bnsums[t] * invN;
        float var = bnsums[64 + t] * invN - mean * mean;
        float sc = gamma[t] * rsqrtf(var + 1e-5f);
        ss_scale[t] = sc;
        ss_shift[t] = beta[t] - mean * sc;
    }
    __syncthreads();
    int n0 = blockIdx.x * 32;
    int c = t & 63;
    float sc = ss_scale[c], sh = ss_shift[c];
#pragma unroll
    for (int i = 0; i < 8; ++i) {
        int li = t + i * 256;
        int gidx = n0 * 64 + li;
        float hn = 0.f;
        if (gidx < N * 64) {
            float o = outbuf_in[gidx] * sc + sh;
            o = (o > 0.f) ? o : 0.01f * o;
            hn = h[gidx] + o;
            h[gidx] = hn;
        }
        hb[li] = f2bf(hn);
    }
    __syncthreads();
    // MFMA phase (layer l+1 weights)
    int wave = t >> 6, lane = t & 63;
    int quad = lane >> 4, nn = lane & 15;
    const ushort_t* apA = hb + nn * 64 + quad * 8;
    const ushort_t* apB = hb + (16 + nn) * 64 + quad * 8;
    short8 aA0 = *(const short8*)apA;
    short8 aA1 = *(const short8*)(apA + 32);
    short8 aB0 = *(const short8*)apB;
    short8 aB1 = *(const short8*)(apB + 32);
    int ct_start = (wave < 2) ? wave * 8 : (16 + (wave - 2) * 7);
    int ct_cnt = (wave < 2) ? 8 : 7;
    for (int i = 0; i < ct_cnt; ++i) {
        int ct = ct_start + i;
        const ushort_t* bp = Wall_arr + (size_t)ct * 1024 + lane * 8;
        short8 b0 = *(const short8*)bp;
        short8 b1 = *(const short8*)(bp + 512);
        float4v cA = {0.f, 0.f, 0.f, 0.f};
        float4v cB = {0.f, 0.f, 0.f, 0.f};
        cA = __builtin_amdgcn_mfma_f32_16x16x32_bf16(aA0, b0, cA, 0, 0, 0);
        cA = __builtin_amdgcn_mfma_f32_16x16x32_bf16(aA1, b1, cA, 0, 0, 0);
        cB = __builtin_amdgcn_mfma_f32_16x16x32_bf16(aB0, b0, cB, 0, 0, 0);
        cB = __builtin_amdgcn_mfma_f32_16x16x32_bf16(aB1, b1, cB, 0, 0, 0);
        int col = ct * 16 + nn;
        float bias = Wall_bias[col];
#pragma unroll
        for (int g = 0; g < 2; ++g) {
            float4v cc2 = (g == 0) ? cA : cB;
            int nbase = n0 + g * 16 + quad * 4;
            if (col < 384) {
                int cm;
                if (col < 128) cm = col;
                else if (col < 256) { int cv = col - 128; cm = 128 + ((cv >> 1) << 2) + (cv & 1); }
                else { int cv = col - 256; cm = 128 + ((cv >> 1) << 2) + 2 + (cv & 1); }
                ushort_t* qp = qkv + (size_t)nbase * 384 + cm;
#pragma unroll
                for (int r = 0; r < 4; ++r)
                    if (nbase + r < N) qp[(size_t)r * 384] = f2bf(cc2[r] + bias);
            } else if (col < 448) {
                float* op = outbuf + (size_t)nbase * 64 + (col - 448 + 64);
#pragma unroll
                for (int r = 0; r < 4; ++r)
                    if (nbase + r < N) op[(size_t)r * 64] = cc2[r] + bias;
            } else if (col < 466) {
                float* qp2 = qcbuf + (size_t)nbase * 20 + (col - 448);
#pragma unroll
                for (int r = 0; r < 4; ++r)
                    if (nbase + r < N) qp2[(size_t)r * 20] = cc2[r] + bias;
            }
        }
    }
}

// ---------------- attention + fused BN partial stats (scalarized bounds) ----------------

__global__ __launch_bounds__(256) void attn_kernel(
    const ushort_t* __restrict__ qkv, const float* __restrict__ qcbuf,
    const int* __restrict__ csr_src, const float* __restrict__ ea_perm,
    const int* __restrict__ rowptr,
    const float* __restrict__ Wc, const float* __restrict__ bcb,
    float* __restrict__ outbuf, float* __restrict__ part, int N) {
    __shared__ float Wc_s[1024];
    __shared__ float bc_s[128];
    __shared__ float sred[4][64];
    int t = threadIdx.x;
    for (int i = t; i < 1024; i += 256) Wc_s[i] = Wc[i];
    if (t < 128) bc_s[t] = bcb[t];
    __syncthreads();
    int lane = t & 63, wid = t >> 6;
    int half = lane >> 5, l31 = lane & 31;
    const char* qkvb = (const char*)qkv;
    float sa0 = 0.f, sa1 = 0.f, sq0 = 0.f, sq1 = 0.f;
    for (int n = blockIdx.x * 4 + wid; n < N; n += gridDim.x * 4) {
        int start = __builtin_amdgcn_readfirstlane(rowptr[n]);
        int end = __builtin_amdgcn_readfirstlane(rowptr[n + 1]);
        float2* op = (float2*)(outbuf + (size_t)n * 64 + 2 * l31);
        if (end <= start) {
            if (half == 0) {
                float2 cur = *op;
                sa0 += cur.x; sq0 += cur.x * cur.x;
                sa1 += cur.y; sq1 += cur.y * cur.y;
            }
            continue;
        }
        unsigned qraw = *(const unsigned*)(qkvb + (size_t)n * 768 + 4 * lane);
        float qx = bfu_lo(qraw), qy = bfu_hi(qraw);
        const float4 qcA = *(const float4*)(qcbuf + (size_t)n * 20 + half * 8);
        const float4 qcB = *(const float4*)(qcbuf + (size_t)n * 20 + half * 8 + 4);
        float qb = qcbuf[(size_t)n * 20 + 16 + half];
        float lsum = 0.f, ax = 0.f, ay = 0.f;
        float4 se0 = {0.f, 0.f, 0.f, 0.f}, se1 = {0.f, 0.f, 0.f, 0.f};
        for (int seg = start; seg < end; seg += 64) {
            int segcnt = min(64, end - seg);
            int li = (lane < segcnt) ? lane : (segcnt - 1);
            int offL = csr_src[seg + li];
            uint2 kvc[4], kvn[4];
#pragma unroll
            for (int j = 0; j < 4; ++j) {
                int idx = (j < segcnt) ? j : (segcnt - 1);
                int o = __shfl(offL, idx);
                kvc[j] = *(const uint2*)(qkvb + (size_t)(unsigned)o + 8 * lane);
            }
            for (int base = 0; base < segcnt; base += 4) {
                int nb2 = base + 4;
                if (nb2 < segcnt) {
#pragma unroll
                    for (int j = 0; j < 4; ++j) {
                        int idx = (nb2 + j < segcnt) ? (nb2 + j) : (segcnt - 1);
                        int o = __shfl(offL, idx);
                        kvn[j] = *(const uint2*)(qkvb + (size_t)(unsigned)o + 8 * lane);
                    }
                }
                float4 a0[4], a1[4];
                float dt[4];
#pragma unroll
                for (int j = 0; j < 4; ++j) {
                    int gi = seg + base + ((base + j < segcnt) ? j : 0);
                    const float* eap = ea_perm + (size_t)gi * 8;
                    a0[j] = *(const float4*)eap;
                    a1[j] = *(const float4*)(eap + 4);
                    dt[j] = qx * bfu_lo(kvc[j].x) + qy * bfu_hi(kvc[j].x);
                }
#pragma unroll
                for (int m = 1; m <= 16; m <<= 1) {
#pragma unroll
                    for (int j = 0; j < 4; ++j) dt[j] += __shfl_xor(dt[j], m);
                }
#pragma unroll
                for (int j = 0; j < 4; ++j) {
                    float s0 = dt[j] * 0.125f
                        + qcA.x * a0[j].x + qcA.y * a0[j].y + qcA.z * a0[j].z + qcA.w * a0[j].w
                        + qcB.x * a1[j].x + qcB.y * a1[j].y + qcB.z * a1[j].z + qcB.w * a1[j].w
                        + qb;
                    float p = (base + j < segcnt) ? __expf(fmaxf(s0, -60.f)) : 0.f;
                    lsum += p;
                    ax += p * bfu_lo(kvc[j].y);
                    ay += p * bfu_hi(kvc[j].y);
                    se0.x += p * a0[j].x; se0.y += p * a0[j].y;
                    se0.z += p * a0[j].z; se0.w += p * a0[j].w;
                    se1.x += p * a1[j].x; se1.y += p * a1[j].y;
                    se1.z += p * a1[j].z; se1.w += p * a1[j].w;
                }
#pragma unroll
                for (int j = 0; j < 4; ++j) kvc[j] = kvn[j];
            }
        }
        int j0 = half * 64 + 2 * l31;
        float w0 = lsum * bc_s[j0], w1 = lsum * bc_s[j0 + 1];
        w0 += se0.x * Wc_s[0 * 128 + j0] + se0.y * Wc_s[1 * 128 + j0] +
              se0.z * Wc_s[2 * 128 + j0] + se0.w * Wc_s[3 * 128 + j0] +
              se1.x * Wc_s[4 * 128 + j0] + se1.y * Wc_s[5 * 128 + j0] +
              se1.z * Wc_s[6 * 128 + j0] + se1.w * Wc_s[7 * 128 + j0];
        w1 += se0.x * Wc_s[0 * 128 + j0 + 1] + se0.y * Wc_s[1 * 128 + j0 + 1] +
              se0.z * Wc_s[2 * 128 + j0 + 1] + se0.w * Wc_s[3 * 128 + j0 + 1] +
              se1.x * Wc_s[4 * 128 + j0 + 1] + se1.y * Wc_s[5 * 128 + j0 + 1] +
              se1.z * Wc_s[6 * 128 + j0 + 1] + se1.w * Wc_s[7 * 128 + j0 + 1];
        float inv = 1.f / lsum;
        float ox = (ax + w0) * inv, oy = (ay + w1) * inv;
        float px = __shfl_xor(ox, 32), py = __shfl_xor(oy, 32);
        ox = 0.5f * (ox + px);
        oy = 0.5f * (oy + py);
        if (half == 0) {
            float2 cur = *op;
            float fx = cur.x + ox, fy = cur.y + oy;
            *op = make_float2(fx, fy);
            sa0 += fx; sq0 += fx * fx;
            sa1 += fy; sq1 += fy * fy;
        }
    }
    __syncthreads();
    if (half == 0) { sred[wid][2 * l31] = sa0; sred[wid][2 * l31 + 1] = sa1; }
    __syncthreads();
    if (t < 64) part[(size_t)blockIdx.x * 128 + t] =
        sred[0][t] + sred[1][t] + sred[2][t] + sred[3][t];
    __syncthreads();
    if (half == 0) { sred[wid][2 * l31] = sq0; sred[wid][2 * l31 + 1] = sq1; }
    __syncthreads();
    if (t < 64) part[(size_t)blockIdx.x * 128 + 64 + t] =
        sred[0][t] + sred[1][t] + sred[2][t] + sred[3][t];
}

// ---------------- BN reduce + final-layer apply w/ gate ----------------

__global__ __launch_bounds__(256) void bnreduce_kernel(const float* __restrict__ part,
                                                       float* __restrict__ bnsums) {
    int s = blockIdx.x;  // 0..127
    int t = threadIdx.x;
    float a = 0.f;
    for (int b = t; b < ATTN_BLOCKS; b += 256) a += part[(size_t)b * 128 + s];
    __shared__ float sh[256];
    sh[t] = a;
    __syncthreads();
    for (int d = 128; d; d >>= 1) {
        if (t < d) sh[t] += sh[t + d];
        __syncthreads();
    }
    if (t == 0) bnsums[s] = sh[0];
}

__global__ __launch_bounds__(256) void bnapply_kernel(
    const float* __restrict__ outbuf, const float* __restrict__ bnsums,
    const float* __restrict__ gamma, const float* __restrict__ beta,
    const float* __restrict__ gate_W, const float* __restrict__ gate_b,
    float* __restrict__ h, float* __restrict__ gatebuf, int N) {
    int idx = blockIdx.x * 256 + threadIdx.x;
    if (idx >= N * 64) return;
    int c = idx & 63, n = idx >> 6;
    float invN = 1.f / (float)N;
    float mean = bnsums[c] * invN;
    float var = bnsums[64 + c] * invN - mean * mean;
    float scale = gamma[c] * rsqrtf(var + 1e-5f);
    float shift = beta[c] - mean * scale;
    float o = outbuf[idx] * scale + shift;
    o = (o > 0.f) ? o : 0.01f * o;
    float hn = h[idx] + o;
    h[idx] = hn;
    float g = hn * gate_W[c];
#pragma unroll
    for (int off = 32; off; off >>= 1) g += __shfl_xor(g, off);
    if (c == 0) gatebuf[n] = g + gate_b[0];
}

// ---------------- pooling (max fused into acc) ----------------

__global__ __launch_bounds__(256) void pool_acc_kernel(
    const float* __restrict__ h, const float* __restrict__ gatebuf,
    const int* __restrict__ batch,
    float* __restrict__ pacc, float* __restrict__ pden, int N) {
    int b = blockIdx.x >> 3, chunk = blockIdx.x & 7;
    int lo = 0, hi = N;
    while (lo < hi) { int mid = (lo + hi) >> 1; if (batch[mid] < b) lo = mid + 1; else hi = mid; }
    int start = lo;
    lo = start; hi = N;
    while (lo < hi) { int mid = (lo + hi) >> 1; if (batch[mid] <= b) lo = mid + 1; else hi = mid; }
    int end = lo;
    int t = threadIdx.x, lane = t & 63, wid = t >> 6;
    __shared__ float sm[4];
    // per-graph max (redundant across the 8 chunk-blocks; cheap)
    float mx = -1e30f;
    for (int n = start + t; n < end; n += 256) mx = fmaxf(mx, gatebuf[n]);
#pragma unroll
    for (int off = 32; off; off >>= 1) mx = fmaxf(mx, __shfl_xor(mx, off));
    if (lane == 0) sm[wid] = mx;
    __syncthreads();
    float mb = fmaxf(fmaxf(sm[0], sm[1]), fmaxf(sm[2], sm[3]));
    int gwid = chunk * 4 + wid;
    float acc = 0.f, den = 0.f;
    for (int n = start + gwid; n < end; n += 32) {
        float ge = __expf(gatebuf[n] - mb);
        acc += ge * h[(size_t)n * 64 + lane];
        den += ge;
    }
    __shared__ float sacc[4][64];
    __shared__ float sden[4];
    sacc[wid][lane] = acc;
    if (lane == 0) sden[wid] = den;
    __syncthreads();
    if (wid == 0) {
        pacc[(size_t)blockIdx.x * 64 + lane] =
            sacc[0][lane] + sacc[1][lane] + sacc[2][lane] + sacc[3][lane];
        if (lane == 0) pden[blockIdx.x] = sden[0] + sden[1] + sden[2] + sden[3];
    }
}

__global__ void pool_fin_kernel(const float* __restrict__ pacc, const float* __restrict__ pden,
                                const float* __restrict__ out_W, const float* __restrict__ out_b,
                                float* __restrict__ out) {
    int b = blockIdx.x, c = threadIdx.x;
    float pc = 0.f, dv = 0.f;
#pragma unroll
    for (int j = 0; j < 8; ++j) {
        pc += pacc[(size_t)(b * 8 + j) * 64 + c];
        dv += pden[b * 8 + j];
    }
    float s = pc * out_W[c];
#pragma unroll
    for (int off = 32; off; off >>= 1) s += __shfl_xor(s, off);
    if (c == 0) {
        if (dv <= 0.f) dv = 1.f;
        float v = s / dv + out_b[0];
        out[b] = 1.f / (1.f + __expf(-v));
    }
}

// ---------------- host ----------------

extern "C" void kernel_launch(void* const* d_in, const int* in_sizes, int n_in,
                              void* d_out, int out_size, void* d_ws, size_t ws_size,
                              hipStream_t stream) {
    const float* x         = (const float*)d_in[0];
    const float* edge_attr = (const float*)d_in[1];
    const int*   edge_src  = (const int*)d_in[2];
    const int*   edge_dst  = (const int*)d_in[3];
    const int*   batch     = (const int*)d_in[4];
    const float* node_W    = (const float*)d_in[5];
    const float* node_b    = (const float*)d_in[6];
    const float* edge_W    = (const float*)d_in[7];
    const float* edge_b    = (const float*)d_in[8];
    const float* Wq        = (const float*)d_in[9];
    const float* bq        = (const float*)d_in[10];
    const float* Wk        = (const float*)d_in[11];
    const float* bk        = (const float*)d_in[12];
    const float* Wv        = (const float*)d_in[13];
    const float* bv        = (const float*)d_in[14];
    const float* We        = (const float*)d_in[15];
    const float* be        = (const float*)d_in[16];
    const float* Wskip     = (const float*)d_in[17];
    const float* bskip     = (const float*)d_in[18];
    const float* gamma     = (const float*)d_in[19];
    const float* beta      = (const float*)d_in[20];
    const float* gate_W    = (const float*)d_in[21];
    const float* gate_b    = (const float*)d_in[22];
    const float* out_W     = (const float*)d_in[23];
    const float* out_b     = (const float*)d_in[24];
    float* out = (float*)d_out;

    const int N = in_sizes[0] / 16;
    const int E = in_sizes[2];

    char* ws = (char*)d_ws;
    size_t off = 0;
    auto alloc = [&](size_t bytes) {
        size_t o = off;
        off += (bytes + 255) & ~(size_t)255;
        return o;
    };
    float*    h        = (float*)(ws + alloc((size_t)N * 64 * 4));
    ushort_t* h_bf     = (ushort_t*)(ws + alloc((size_t)N * 64 * 2));
    ushort_t* qkv      = (ushort_t*)(ws + alloc((size_t)N * 384 * 2));
    float*    outbuf   = (float*)(ws + alloc((size_t)N * 64 * 4));
    float*    qcbuf    = (float*)(ws + alloc((size_t)N * 20 * 4));
    int*      rowptr   = (int*)(ws + alloc((size_t)(N + 1) * 4));
    int*      cursor   = (int*)(ws + alloc((size_t)N * 4));
    int*      counts   = (int*)(ws + alloc((size_t)N * 4));
    int*      bsums    = (int*)(ws + alloc(1024));
    int*      csr_src  = (int*)(ws + alloc((size_t)E * 4));
    float*    ea_perm  = (float*)(ws + alloc((size_t)E * 8 * 4));
    float*    Wc       = (float*)(ws + alloc(2 * 1024 * 4));
    float*    bcb      = (float*)(ws + alloc(2 * 128 * 4));
    ushort_t* Wall_arr = (ushort_t*)(ws + alloc(2 * 32768 * 2));
    float*    Wall_b   = (float*)(ws + alloc(2 * 512 * 4));
    float*    bnsums   = (float*)(ws + alloc(128 * 4));
    float*    gatebuf  = (float*)(ws + alloc((size_t)N * 4));
    float*    pacc     = (float*)(ws + alloc((size_t)ATTN_BLOCKS * 128 * 4));
    float*    pden     = (float*)(ws + alloc(512 * 4));
    if (off > ws_size) return;

    int O0 = (N * 64 + 255) / 256;
    int O1 = O0 + (N + 255) / 256;
    int O2 = O1 + 9;
    int O3 = O2 + 228;
    setup_kernel<<<O3, 256, 0, stream>>>(
        x, node_W, node_b, edge_W, edge_b, We, be, Wq, bq, Wk, bk, Wv, bv, Wskip, bskip,
        h, h_bf, counts, Wc, bcb, Wall_arr, Wall_b, O0, O1, O2, N);
    combine2_kernel<<<10, 256, 0, stream>>>(Wq, bq, Wc, bcb, Wall_arr, Wall_b);

    csr_count_kernel<<<(E + 255) / 256, 256, 0, stream>>>(edge_dst, counts, E);
    int nb = (N + 255) / 256;
    scan1_kernel<<<nb, 256, 0, stream>>>(counts, rowptr, bsums, N);
    scan3_kernel<<<nb, 256, 0, stream>>>(rowptr, bsums, cursor, N, E, nb);
    csr_fill_kernel<<<(E + 255) / 256, 256, 0, stream>>>(edge_dst, edge_src, edge_attr,
                                                         cursor, csr_src, ea_perm, E);

    // layer 0
    qkv_mfma_kernel<<<(N + 31) / 32, 256, 0, stream>>>(
        h_bf, Wall_arr, Wall_b, qkv, outbuf, qcbuf, N);
    attn_kernel<<<ATTN_BLOCKS, 256, 0, stream>>>(qkv, qcbuf, csr_src, ea_perm,
                                                 rowptr, Wc, bcb, outbuf, pacc, N);
    bnreduce_kernel<<<128, 256, 0, stream>>>(pacc, bnsums);
    // fused: BN-apply(l0) + qkv(l1)
    bnqkv_kernel<<<(N + 31) / 32, 256, 0, stream>>>(
        outbuf, bnsums, gamma, beta, h,
        Wall_arr + 32768, Wall_b + 512, qkv, outbuf, qcbuf, N);

    // layer 1
    attn_kernel<<<ATTN_BLOCKS, 256, 0, stream>>>(qkv, qcbuf, csr_src, ea_perm,
                                                 rowptr, Wc + 1024, bcb + 128,
                                                 outbuf, pacc, N);
    bnreduce_kernel<<<128, 256, 0, stream>>>(pacc, bnsums);
    bnapply_kernel<<<(N * 64 + 255) / 256, 256, 0, stream>>>(
        outbuf, bnsums, gamma + 64, beta + 64, gate_W, gate_b, h, gatebuf, N);

    pool_acc_kernel<<<512, 256, 0, stream>>>(h, gatebuf, batch, pacc, pden, N);
    pool_fin_kernel<<<64, 64, 0, stream>>>(pacc, pden, out_W, out_b, out);
}

// Round 16
// 439.931 us; speedup vs baseline: 1.1179x; 1.0050x over previous
//
#include <hip/hip_runtime.h>
#include <hip/hip_bf16.h>

typedef unsigned short ushort_t;
typedef __attribute__((ext_vector_type(8))) short short8;
typedef __attribute__((ext_vector_type(4))) float float4v;

#define ATTN_BLOCKS 2048

__device__ __forceinline__ float bfu_lo(unsigned u) {
    return __uint_as_float(u << 16);
}
__device__ __forceinline__ float bfu_hi(unsigned u) {
    return __uint_as_float(u & 0xffff0000u);
}
__device__ __forceinline__ ushort_t f2bf(float f) {
    __hip_bfloat16 h = __float2bfloat16(f);
    return *reinterpret_cast<ushort_t*>(&h);
}

// Wall layout per layer: 30 col-tiles (466 cols used), tile = 1024 ushorts:
//   idx = ct*1024 + kch*512 + lane*8 + j
// cols: 0..127 q | 128..255 k | 256..383 v | 384..447 skip | 448..465 qc

// ---------------- fused setup ----------------

__global__ __launch_bounds__(256) void setup_kernel(
    const float* __restrict__ x, const float* __restrict__ node_W,
    const float* __restrict__ node_b,
    const float* __restrict__ edge_W, const float* __restrict__ edge_b,
    const float* __restrict__ We, const float* __restrict__ be,
    const float* __restrict__ Wq, const float* __restrict__ bq,
    const float* __restrict__ Wk, const float* __restrict__ bk,
    const float* __restrict__ Wv, const float* __restrict__ bv,
    const float* __restrict__ Wskip, const float* __restrict__ bskip,
    float* __restrict__ h, ushort_t* __restrict__ h_bf,
    int* __restrict__ counts,
    float* __restrict__ Wc, float* __restrict__ bcb,
    ushort_t* __restrict__ Wall_arr, float* __restrict__ Wall_bias,
    int O0, int O1, int O2, int N) {
    int b = blockIdx.x, t = threadIdx.x;
    if (b < O0) {
        int idx = b * 256 + t;
        if (idx < N * 64) {
            int n = idx >> 6, c = idx & 63;
            float acc = node_b[c];
#pragma unroll
            for (int j = 0; j < 16; ++j) acc += x[n * 16 + j] * node_W[j * 64 + c];
            h[idx] = acc;
            h_bf[idx] = f2bf(acc);
        }
    } else if (b < O1) {
        int i = (b - O0) * 256 + t;
        if (i < N) counts[i] = 0;
    } else if (b < O2) {
        int tid = (b - O1) * 256 + t;
        if (tid < 2048) {
            int l = tid >> 10, d = (tid >> 7) & 7, j = tid & 127;
            float s = 0.f;
            for (int m = 0; m < 64; ++m) s += edge_W[d * 64 + m] * We[l * 8192 + m * 128 + j];
            Wc[l * 1024 + d * 128 + j] = s;
        } else if (tid < 2048 + 256) {
            int u = tid - 2048;
            int l = u >> 7, j = u & 127;
            float s = be[l * 128 + j];
            for (int m = 0; m < 64; ++m) s += edge_b[m] * We[l * 8192 + m * 128 + j];
            bcb[l * 128 + j] = s;
        }
    } else {
        int tid = (b - O2) * 256 + t;
        if (tid < 2 * 28672) {
            int l = tid / 28672, u = tid % 28672;
            int j = u & 7, ln = (u >> 3) & 63, kch = (u >> 9) & 1, ct = u >> 10;
            int nn = ln & 15, quad = ln >> 4;
            int k = kch * 32 + quad * 8 + j;
            int col = ct * 16 + nn;
            float v;
            if (col < 128)      v = Wq[l * 8192 + k * 128 + col];
            else if (col < 256) v = Wk[l * 8192 + k * 128 + col - 128];
            else if (col < 384) v = Wv[l * 8192 + k * 128 + col - 256];
            else                v = Wskip[l * 4096 + k * 64 + col - 384];
            Wall_arr[(size_t)l * 32768 + ct * 1024 + kch * 512 + ln * 8 + j] = f2bf(v);
        } else if (tid < 2 * 28672 + 2 * 448) {
            int u = tid - 2 * 28672;
            int l = u / 448, col = u % 448;
            float v;
            if (col < 128)      v = bq[l * 128 + col];
            else if (col < 256) v = bk[l * 128 + col - 128];
            else if (col < 384) v = bv[l * 128 + col - 256];
            else                v = bskip[l * 64 + col - 384];
            Wall_bias[l * 512 + col] = v;
        }
    }
}

// combine2: qc composed weights into Wall fragments
__global__ void combine2_kernel(const float* __restrict__ Wq, const float* __restrict__ bq,
                                const float* __restrict__ Wc, const float* __restrict__ bcb,
                                ushort_t* __restrict__ Wall_arr, float* __restrict__ Wall_bias) {
    int tid = blockIdx.x * 256 + threadIdx.x;
    if (tid < 2304) {
        int l = tid / 1152, u = tid % 1152, k = u / 18, j = u % 18;
        float s = 0.f;
        if (j < 16) {
            int hh = j >> 3, d = j & 7;
            for (int c = 0; c < 64; ++c)
                s += Wq[l * 8192 + k * 128 + hh * 64 + c] * Wc[l * 1024 + d * 128 + hh * 64 + c];
        } else {
            int hh = j - 16;
            for (int c = 0; c < 64; ++c)
                s += Wq[l * 8192 + k * 128 + hh * 64 + c] * bcb[l * 128 + hh * 64 + c];
        }
        s *= 0.125f;
        int col = 448 + j;
        int ct = col >> 4, nn = col & 15;
        int kch = k >> 5, quad = (k >> 3) & 3, jj = k & 7;
        int ln = quad * 16 + nn;
        Wall_arr[(size_t)l * 32768 + ct * 1024 + kch * 512 + ln * 8 + jj] = f2bf(s);
    } else if (tid < 2304 + 36) {
        int u = tid - 2304;
        int l = u / 18, j = u % 18;
        float s = 0.f;
        if (j < 16) {
            int hh = j >> 3, d = j & 7;
            for (int c = 0; c < 64; ++c)
                s += bq[l * 128 + hh * 64 + c] * Wc[l * 1024 + d * 128 + hh * 64 + c];
        } else {
            int hh = j - 16;
            for (int c = 0; c < 64; ++c)
                s += bq[l * 128 + hh * 64 + c] * bcb[l * 128 + hh * 64 + c];
        }
        Wall_bias[l * 512 + 448 + j] = 0.125f * s;
    }
}

// ---------------- CSR build ----------------

__global__ void csr_count_kernel(const int* __restrict__ dst, int* __restrict__ counts, int E) {
    int e = blockIdx.x * 256 + threadIdx.x;
    if (e < E) atomicAdd(&counts[dst[e]], 1);
}

__global__ void scan1_kernel(const int* __restrict__ counts, int* __restrict__ rowptr,
                             int* __restrict__ bsums, int N) {
    __shared__ int s[256];
    int t = threadIdx.x, i = blockIdx.x * 256 + t;
    int v = (i < N) ? counts[i] : 0;
    s[t] = v;
    __syncthreads();
    for (int d = 1; d < 256; d <<= 1) {
        int x = (t >= d) ? s[t - d] : 0;
        __syncthreads();
        s[t] += x;
        __syncthreads();
    }
    if (i < N) rowptr[i] = s[t] - v;
    if (t == 255) bsums[blockIdx.x] = s[255];
}

// scan3 with scan2 folded in
__global__ void scan3_kernel(int* __restrict__ rowptr, const int* __restrict__ bsums,
                             int* __restrict__ cursor, int N, int E, int nb) {
    __shared__ int sh[256];
    int t = threadIdx.x;
    int v = (t < nb) ? bsums[t] : 0;
    sh[t] = v;
    __syncthreads();
    for (int d = 1; d < 256; d <<= 1) {
        int x = (t >= d) ? sh[t - d] : 0;
        __syncthreads();
        sh[t] += x;
        __syncthreads();
    }
    int blk = blockIdx.x;
    int offv = (blk == 0) ? 0 : sh[blk - 1];
    int i = blk * 256 + t;
    if (i < N) {
        int r = rowptr[i] + offv;
        rowptr[i] = r;
        cursor[i] = r;
    }
    if (i == 0) rowptr[N] = E;
}

__global__ void csr_fill_kernel(const int* __restrict__ dst, const int* __restrict__ src,
                                const float* __restrict__ edge_attr, int* __restrict__ cursor,
                                int* __restrict__ csr_src, float* __restrict__ ea_perm, int E) {
    int e = blockIdx.x * 256 + threadIdx.x;
    if (e < E) {
        int pos = atomicAdd(&cursor[dst[e]], 1);
        csr_src[pos] = src[e] * 768 + 256;
        float4 a0 = *(const float4*)(edge_attr + (size_t)e * 8);
        float4 a1 = *(const float4*)(edge_attr + (size_t)e * 8 + 4);
        *(float4*)(ea_perm + (size_t)pos * 8) = a0;
        *(float4*)(ea_perm + (size_t)pos * 8 + 4) = a1;
    }
}

// ---------------- per-layer MFMA GEMM: [32 x 64] @ [64 x 466] (from global h_bf) ----

__global__ __launch_bounds__(256) void qkv_mfma_kernel(
    const ushort_t* __restrict__ h_bf,
    const ushort_t* __restrict__ Wall_arr, const float* __restrict__ Wall_bias,
    ushort_t* __restrict__ qkv, float* __restrict__ outbuf, float* __restrict__ qcbuf, int N) {
    int wave = threadIdx.x >> 6, lane = threadIdx.x & 63;
    int quad = lane >> 4, nn = lane & 15;
    int n0 = blockIdx.x * 32;
    int nodeA = n0 + nn;       if (nodeA >= N) nodeA = N - 1;
    int nodeB = n0 + 16 + nn;  if (nodeB >= N) nodeB = N - 1;
    const ushort_t* apA = h_bf + (size_t)nodeA * 64 + quad * 8;
    const ushort_t* apB = h_bf + (size_t)nodeB * 64 + quad * 8;
    short8 aA0 = *(const short8*)apA;
    short8 aA1 = *(const short8*)(apA + 32);
    short8 aB0 = *(const short8*)apB;
    short8 aB1 = *(const short8*)(apB + 32);
    int ct_start = (wave < 2) ? wave * 8 : (16 + (wave - 2) * 7);
    int ct_cnt = (wave < 2) ? 8 : 7;
    for (int i = 0; i < ct_cnt; ++i) {
        int ct = ct_start + i;
        const ushort_t* bp = Wall_arr + (size_t)ct * 1024 + lane * 8;
        short8 b0 = *(const short8*)bp;
        short8 b1 = *(const short8*)(bp + 512);
        float4v cA = {0.f, 0.f, 0.f, 0.f};
        float4v cB = {0.f, 0.f, 0.f, 0.f};
        cA = __builtin_amdgcn_mfma_f32_16x16x32_bf16(aA0, b0, cA, 0, 0, 0);
        cA = __builtin_amdgcn_mfma_f32_16x16x32_bf16(aA1, b1, cA, 0, 0, 0);
        cB = __builtin_amdgcn_mfma_f32_16x16x32_bf16(aB0, b0, cB, 0, 0, 0);
        cB = __builtin_amdgcn_mfma_f32_16x16x32_bf16(aB1, b1, cB, 0, 0, 0);
        int col = ct * 16 + nn;
        float bias = Wall_bias[col];
#pragma unroll
        for (int g = 0; g < 2; ++g) {
            float4v c = (g == 0) ? cA : cB;
            int nbase = n0 + g * 16 + quad * 4;
            if (col < 384) {
                int cm;
                if (col < 128) cm = col;
                else if (col < 256) { int cc = col - 128; cm = 128 + ((cc >> 1) << 2) + (cc & 1); }
                else { int cc = col - 256; cm = 128 + ((cc >> 1) << 2) + 2 + (cc & 1); }
                ushort_t* qp = qkv + (size_t)nbase * 384 + cm;
#pragma unroll
                for (int r = 0; r < 4; ++r)
                    if (nbase + r < N) qp[(size_t)r * 384] = f2bf(c[r] + bias);
            } else if (col < 448) {
                float* op = outbuf + (size_t)nbase * 64 + (col - 448 + 64);
#pragma unroll
                for (int r = 0; r < 4; ++r)
                    if (nbase + r < N) op[(size_t)r * 64] = c[r] + bias;
            } else if (col < 466) {
                float* qp2 = qcbuf + (size_t)nbase * 20 + (col - 448);
#pragma unroll
                for (int r = 0; r < 4; ++r)
                    if (nbase + r < N) qp2[(size_t)r * 20] = c[r] + bias;
            }
        }
    }
}

// ---------------- fused BN-apply(l) + qkv-MFMA(l+1): 32 nodes/block ----------------

__global__ __launch_bounds__(256) void bnqkv_kernel(
    const float* __restrict__ outbuf_in, const float* __restrict__ bnsums,
    const float* __restrict__ gamma, const float* __restrict__ beta,
    float* __restrict__ h,
    const ushort_t* __restrict__ Wall_arr, const float* __restrict__ Wall_bias,
    ushort_t* __restrict__ qkv, float* __restrict__ outbuf, float* __restrict__ qcbuf, int N) {
    __shared__ ushort_t hb[32 * 64];
    __shared__ float ss_scale[64], ss_shift[64];
    int t = threadIdx.x;
    if (t < 64) {
        float invN = 1.f / (float)N;
        float mean = bnsums[t] * invN;
        float var = bnsums[64 + t] * invN - mean * mean;
        float sc = gamma[t] * rsqrtf(var + 1e-5f);
        ss_scale[t] = sc;
        ss_shift[t] = beta[t] - mean * sc;
    }
    __syncthreads();
    int n0 = blockIdx.x * 32;
    int c = t & 63;
    float sc = ss_scale[c], sh = ss_shift[c];
#pragma unroll
    for (int i = 0; i < 8; ++i) {
        int li = t + i * 256;
        int gidx = n0 * 64 + li;
        float hn = 0.f;
        if (gidx < N * 64) {
            float o = outbuf_in[gidx] * sc + sh;
            o = (o > 0.f) ? o : 0.01f * o;
            hn = h[gidx] + o;
            h[gidx] = hn;
        }
        hb[li] = f2bf(hn);
    }
    __syncthreads();
    int wave = t >> 6, lane = t & 63;
    int quad = lane >> 4, nn = lane & 15;
    const ushort_t* apA = hb + nn * 64 + quad * 8;
    const ushort_t* apB = hb + (16 + nn) * 64 + quad * 8;
    short8 aA0 = *(const short8*)apA;
    short8 aA1 = *(const short8*)(apA + 32);
    short8 aB0 = *(const short8*)apB;
    short8 aB1 = *(const short8*)(apB + 32);
    int ct_start = (wave < 2) ? wave * 8 : (16 + (wave - 2) * 7);
    int ct_cnt = (wave < 2) ? 8 : 7;
    for (int i = 0; i < ct_cnt; ++i) {
        int ct = ct_start + i;
        const ushort_t* bp = Wall_arr + (size_t)ct * 1024 + lane * 8;
        short8 b0 = *(const short8*)bp;
        short8 b1 = *(const short8*)(bp + 512);
        float4v cA = {0.f, 0.f, 0.f, 0.f};
        float4v cB = {0.f, 0.f, 0.f, 0.f};
        cA = __builtin_amdgcn_mfma_f32_16x16x32_bf16(aA0, b0, cA, 0, 0, 0);
        cA = __builtin_amdgcn_mfma_f32_16x16x32_bf16(aA1, b1, cA, 0, 0, 0);
        cB = __builtin_amdgcn_mfma_f32_16x16x32_bf16(aB0, b0, cB, 0, 0, 0);
        cB = __builtin_amdgcn_mfma_f32_16x16x32_bf16(aB1, b1, cB, 0, 0, 0);
        int col = ct * 16 + nn;
        float bias = Wall_bias[col];
#pragma unroll
        for (int g = 0; g < 2; ++g) {
            float4v cc2 = (g == 0) ? cA : cB;
            int nbase = n0 + g * 16 + quad * 4;
            if (col < 384) {
                int cm;
                if (col < 128) cm = col;
                else if (col < 256) { int cv = col - 128; cm = 128 + ((cv >> 1) << 2) + (cv & 1); }
                else { int cv = col - 256; cm = 128 + ((cv >> 1) << 2) + 2 + (cv & 1); }
                ushort_t* qp = qkv + (size_t)nbase * 384 + cm;
#pragma unroll
                for (int r = 0; r < 4; ++r)
                    if (nbase + r < N) qp[(size_t)r * 384] = f2bf(cc2[r] + bias);
            } else if (col < 448) {
                float* op = outbuf + (size_t)nbase * 64 + (col - 448 + 64);
#pragma unroll
                for (int r = 0; r < 4; ++r)
                    if (nbase + r < N) op[(size_t)r * 64] = cc2[r] + bias;
            } else if (col < 466) {
                float* qp2 = qcbuf + (size_t)nbase * 20 + (col - 448);
#pragma unroll
                for (int r = 0; r < 4; ++r)
                    if (nbase + r < N) qp2[(size_t)r * 20] = cc2[r] + bias;
            }
        }
    }
}

// ---------------- attention + fused BN partial stats (scalarized bounds) ----------------

__global__ __launch_bounds__(256) void attn_kernel(
    const ushort_t* __restrict__ qkv, const float* __restrict__ qcbuf,
    const int* __restrict__ csr_src, const float* __restrict__ ea_perm,
    const int* __restrict__ rowptr,
    const float* __restrict__ Wc, const float* __restrict__ bcb,
    float* __restrict__ outbuf, float* __restrict__ part, int N) {
    __shared__ float Wc_s[1024];
    __shared__ float bc_s[128];
    __shared__ float sred[4][64];
    int t = threadIdx.x;
    for (int i = t; i < 1024; i += 256) Wc_s[i] = Wc[i];
    if (t < 128) bc_s[t] = bcb[t];
    __syncthreads();
    int lane = t & 63, wid = t >> 6;
    int half = lane >> 5, l31 = lane & 31;
    const char* qkvb = (const char*)qkv;
    float sa0 = 0.f, sa1 = 0.f, sq0 = 0.f, sq1 = 0.f;
    for (int n = blockIdx.x * 4 + wid; n < N; n += gridDim.x * 4) {
        int start = __builtin_amdgcn_readfirstlane(rowptr[n]);
        int end = __builtin_amdgcn_readfirstlane(rowptr[n + 1]);
        float2* op = (float2*)(outbuf + (size_t)n * 64 + 2 * l31);
        if (end <= start) {
            if (half == 0) {
                float2 cur = *op;
                sa0 += cur.x; sq0 += cur.x * cur.x;
                sa1 += cur.y; sq1 += cur.y * cur.y;
            }
            continue;
        }
        unsigned qraw = *(const unsigned*)(qkvb + (size_t)n * 768 + 4 * lane);
        float qx = bfu_lo(qraw), qy = bfu_hi(qraw);
        const float4 qcA = *(const float4*)(qcbuf + (size_t)n * 20 + half * 8);
        const float4 qcB = *(const float4*)(qcbuf + (size_t)n * 20 + half * 8 + 4);
        float qb = qcbuf[(size_t)n * 20 + 16 + half];
        float lsum = 0.f, ax = 0.f, ay = 0.f;
        float4 se0 = {0.f, 0.f, 0.f, 0.f}, se1 = {0.f, 0.f, 0.f, 0.f};
        for (int seg = start; seg < end; seg += 64) {
            int segcnt = min(64, end - seg);
            int li = (lane < segcnt) ? lane : (segcnt - 1);
            int offL = csr_src[seg + li];
            uint2 kvc[4], kvn[4];
#pragma unroll
            for (int j = 0; j < 4; ++j) {
                int idx = (j < segcnt) ? j : (segcnt - 1);
                int o = __shfl(offL, idx);
                kvc[j] = *(const uint2*)(qkvb + (size_t)(unsigned)o + 8 * lane);
            }
            for (int base = 0; base < segcnt; base += 4) {
                int nb2 = base + 4;
                if (nb2 < segcnt) {
#pragma unroll
                    for (int j = 0; j < 4; ++j) {
                        int idx = (nb2 + j < segcnt) ? (nb2 + j) : (segcnt - 1);
                        int o = __shfl(offL, idx);
                        kvn[j] = *(const uint2*)(qkvb + (size_t)(unsigned)o + 8 * lane);
                    }
                }
                float4 a0[4], a1[4];
                float dt[4];
#pragma unroll
                for (int j = 0; j < 4; ++j) {
                    int gi = seg + base + ((base + j < segcnt) ? j : 0);
                    const float* eap = ea_perm + (size_t)gi * 8;
                    a0[j] = *(const float4*)eap;
                    a1[j] = *(const float4*)(eap + 4);
                    dt[j] = qx * bfu_lo(kvc[j].x) + qy * bfu_hi(kvc[j].x);
                }
#pragma unroll
                for (int m = 1; m <= 16; m <<= 1) {
#pragma unroll
                    for (int j = 0; j < 4; ++j) dt[j] += __shfl_xor(dt[j], m);
                }
#pragma unroll
                for (int j = 0; j < 4; ++j) {
                    float s0 = dt[j] * 0.125f
                        + qcA.x * a0[j].x + qcA.y * a0[j].y + qcA.z * a0[j].z + qcA.w * a0[j].w
                        + qcB.x * a1[j].x + qcB.y * a1[j].y + qcB.z * a1[j].z + qcB.w * a1[j].w
                        + qb;
                    float p = (base + j < segcnt) ? __expf(fmaxf(s0, -60.f)) : 0.f;
                    lsum += p;
                    ax += p * bfu_lo(kvc[j].y);
                    ay += p * bfu_hi(kvc[j].y);
                    se0.x += p * a0[j].x; se0.y += p * a0[j].y;
                    se0.z += p * a0[j].z; se0.w += p * a0[j].w;
                    se1.x += p * a1[j].x; se1.y += p * a1[j].y;
                    se1.z += p * a1[j].z; se1.w += p * a1[j].w;
                }
#pragma unroll
                for (int j = 0; j < 4; ++j) kvc[j] = kvn[j];
            }
        }
        int j0 = half * 64 + 2 * l31;
        float w0 = lsum * bc_s[j0], w1 = lsum * bc_s[j0 + 1];
        w0 += se0.x * Wc_s[0 * 128 + j0] + se0.y * Wc_s[1 * 128 + j0] +
              se0.z * Wc_s[2 * 128 + j0] + se0.w * Wc_s[3 * 128 + j0] +
              se1.x * Wc_s[4 * 128 + j0] + se1.y * Wc_s[5 * 128 + j0] +
              se1.z * Wc_s[6 * 128 + j0] + se1.w * Wc_s[7 * 128 + j0];
        w1 += se0.x * Wc_s[0 * 128 + j0 + 1] + se0.y * Wc_s[1 * 128 + j0 + 1] +
              se0.z * Wc_s[2 * 128 + j0 + 1] + se0.w * Wc_s[3 * 128 + j0 + 1] +
              se1.x * Wc_s[4 * 128 + j0 + 1] + se1.y * Wc_s[5 * 128 + j0 + 1] +
              se1.z * Wc_s[6 * 128 + j0 + 1] + se1.w * Wc_s[7 * 128 + j0 + 1];
        float inv = 1.f / lsum;
        float ox = (ax + w0) * inv, oy = (ay + w1) * inv;
        float px = __shfl_xor(ox, 32), py = __shfl_xor(oy, 32);
        ox = 0.5f * (ox + px);
        oy = 0.5f * (oy + py);
        if (half == 0) {
            float2 cur = *op;
            float fx = cur.x + ox, fy = cur.y + oy;
            *op = make_float2(fx, fy);
            sa0 += fx; sq0 += fx * fx;
            sa1 += fy; sq1 += fy * fy;
        }
    }
    __syncthreads();
    if (half == 0) { sred[wid][2 * l31] = sa0; sred[wid][2 * l31 + 1] = sa1; }
    __syncthreads();
    if (t < 64) part[(size_t)blockIdx.x * 128 + t] =
        sred[0][t] + sred[1][t] + sred[2][t] + sred[3][t];
    __syncthreads();
    if (half == 0) { sred[wid][2 * l31] = sq0; sred[wid][2 * l31 + 1] = sq1; }
    __syncthreads();
    if (t < 64) part[(size_t)blockIdx.x * 128 + 64 + t] =
        sred[0][t] + sred[1][t] + sred[2][t] + sred[3][t];
}

// ---------------- BN reduce + final-layer apply w/ gate ----------------

__global__ __launch_bounds__(256) void bnreduce_kernel(const float* __restrict__ part,
                                                       float* __restrict__ bnsums) {
    int s = blockIdx.x;  // 0..127
    int t = threadIdx.x;
    float a = 0.f;
    for (int b = t; b < ATTN_BLOCKS; b += 256) a += part[(size_t)b * 128 + s];
    __shared__ float sh[256];
    sh[t] = a;
    __syncthreads();
    for (int d = 128; d; d >>= 1) {
        if (t < d) sh[t] += sh[t + d];
        __syncthreads();
    }
    if (t == 0) bnsums[s] = sh[0];
}

__global__ __launch_bounds__(256) void bnapply_kernel(
    const float* __restrict__ outbuf, const float* __restrict__ bnsums,
    const float* __restrict__ gamma, const float* __restrict__ beta,
    const float* __restrict__ gate_W, const float* __restrict__ gate_b,
    float* __restrict__ h, float* __restrict__ gatebuf, int N) {
    int idx = blockIdx.x * 256 + threadIdx.x;
    if (idx >= N * 64) return;
    int c = idx & 63, n = idx >> 6;
    float invN = 1.f / (float)N;
    float mean = bnsums[c] * invN;
    float var = bnsums[64 + c] * invN - mean * mean;
    float scale = gamma[c] * rsqrtf(var + 1e-5f);
    float shift = beta[c] - mean * scale;
    float o = outbuf[idx] * scale + shift;
    o = (o > 0.f) ? o : 0.01f * o;
    float hn = h[idx] + o;
    h[idx] = hn;
    float g = hn * gate_W[c];
#pragma unroll
    for (int off = 32; off; off >>= 1) g += __shfl_xor(g, off);
    if (c == 0) gatebuf[n] = g + gate_b[0];
}

// ---------------- pooling (max fused into acc) ----------------

__global__ __launch_bounds__(256) void pool_acc_kernel(
    const float* __restrict__ h, const float* __restrict__ gatebuf,
    const int* __restrict__ batch,
    float* __restrict__ pacc, float* __restrict__ pden, int N) {
    int b = blockIdx.x >> 3, chunk = blockIdx.x & 7;
    int lo = 0, hi = N;
    while (lo < hi) { int mid = (lo + hi) >> 1; if (batch[mid] < b) lo = mid + 1; else hi = mid; }
    int start = lo;
    lo = start; hi = N;
    while (lo < hi) { int mid = (lo + hi) >> 1; if (batch[mid] <= b) lo = mid + 1; else hi = mid; }
    int end = lo;
    int t = threadIdx.x, lane = t & 63, wid = t >> 6;
    __shared__ float sm[4];
    float mx = -1e30f;
    for (int n = start + t; n < end; n += 256) mx = fmaxf(mx, gatebuf[n]);
#pragma unroll
    for (int off = 32; off; off >>= 1) mx = fmaxf(mx, __shfl_xor(mx, off));
    if (lane == 0) sm[wid] = mx;
    __syncthreads();
    float mb = fmaxf(fmaxf(sm[0], sm[1]), fmaxf(sm[2], sm[3]));
    int gwid = chunk * 4 + wid;
    float acc = 0.f, den = 0.f;
    for (int n = start + gwid; n < end; n += 32) {
        float ge = __expf(gatebuf[n] - mb);
        acc += ge * h[(size_t)n * 64 + lane];
        den += ge;
    }
    __shared__ float sacc[4][64];
    __shared__ float sden[4];
    sacc[wid][lane] = acc;
    if (lane == 0) sden[wid] = den;
    __syncthreads();
    if (wid == 0) {
        pacc[(size_t)blockIdx.x * 64 + lane] =
            sacc[0][lane] + sacc[1][lane] + sacc[2][lane] + sacc[3][lane];
        if (lane == 0) pden[blockIdx.x] = sden[0] + sden[1] + sden[2] + sden[3];
    }
}

__global__ void pool_fin_kernel(const float* __restrict__ pacc, const float* __restrict__ pden,
                                const float* __restrict__ out_W, const float* __restrict__ out_b,
                                float* __restrict__ out) {
    int b = blockIdx.x, c = threadIdx.x;
    float pc = 0.f, dv = 0.f;
#pragma unroll
    for (int j = 0; j < 8; ++j) {
        pc += pacc[(size_t)(b * 8 + j) * 64 + c];
        dv += pden[b * 8 + j];
    }
    float s = pc * out_W[c];
#pragma unroll
    for (int off = 32; off; off >>= 1) s += __shfl_xor(s, off);
    if (c == 0) {
        if (dv <= 0.f) dv = 1.f;
        float v = s / dv + out_b[0];
        out[b] = 1.f / (1.f + __expf(-v));
    }
}

// ---------------- host ----------------

extern "C" void kernel_launch(void* const* d_in, const int* in_sizes, int n_in,
                              void* d_out, int out_size, void* d_ws, size_t ws_size,
                              hipStream_t stream) {
    const float* x         = (const float*)d_in[0];
    const float* edge_attr = (const float*)d_in[1];
    const int*   edge_src  = (const int*)d_in[2];
    const int*   edge_dst  = (const int*)d_in[3];
    const int*   batch     = (const int*)d_in[4];
    const float* node_W    = (const float*)d_in[5];
    const float* node_b    = (const float*)d_in[6];
    const float* edge_W    = (const float*)d_in[7];
    const float* edge_b    = (const float*)d_in[8];
    const float* Wq        = (const float*)d_in[9];
    const float* bq        = (const float*)d_in[10];
    const float* Wk        = (const float*)d_in[11];
    const float* bk        = (const float*)d_in[12];
    const float* Wv        = (const float*)d_in[13];
    const float* bv        = (const float*)d_in[14];
    const float* We        = (const float*)d_in[15];
    const float* be        = (const float*)d_in[16];
    const float* Wskip     = (const float*)d_in[17];
    const float* bskip     = (const float*)d_in[18];
    const float* gamma     = (const float*)d_in[19];
    const float* beta      = (const float*)d_in[20];
    const float* gate_W    = (const float*)d_in[21];
    const float* gate_b    = (const float*)d_in[22];
    const float* out_W     = (const float*)d_in[23];
    const float* out_b     = (const float*)d_in[24];
    float* out = (float*)d_out;

    const int N = in_sizes[0] / 16;
    const int E = in_sizes[2];

    char* ws = (char*)d_ws;
    size_t off = 0;
    auto alloc = [&](size_t bytes) {
        size_t o = off;
        off += (bytes + 255) & ~(size_t)255;
        return o;
    };
    float*    h        = (float*)(ws + alloc((size_t)N * 64 * 4));
    ushort_t* h_bf     = (ushort_t*)(ws + alloc((size_t)N * 64 * 2));
    ushort_t* qkv      = (ushort_t*)(ws + alloc((size_t)N * 384 * 2));
    float*    outbuf   = (float*)(ws + alloc((size_t)N * 64 * 4));
    float*    qcbuf    = (float*)(ws + alloc((size_t)N * 20 * 4));
    int*      rowptr   = (int*)(ws + alloc((size_t)(N + 1) * 4));
    int*      cursor   = (int*)(ws + alloc((size_t)N * 4));
    int*      counts   = (int*)(ws + alloc((size_t)N * 4));
    int*      bsums    = (int*)(ws + alloc(1024));
    int*      csr_src  = (int*)(ws + alloc((size_t)E * 4));
    float*    ea_perm  = (float*)(ws + alloc((size_t)E * 8 * 4));
    float*    Wc       = (float*)(ws + alloc(2 * 1024 * 4));
    float*    bcb      = (float*)(ws + alloc(2 * 128 * 4));
    ushort_t* Wall_arr = (ushort_t*)(ws + alloc(2 * 32768 * 2));
    float*    Wall_b   = (float*)(ws + alloc(2 * 512 * 4));
    float*    bnsums   = (float*)(ws + alloc(128 * 4));
    float*    gatebuf  = (float*)(ws + alloc((size_t)N * 4));
    float*    pacc     = (float*)(ws + alloc((size_t)ATTN_BLOCKS * 128 * 4));
    float*    pden     = (float*)(ws + alloc(512 * 4));
    if (off > ws_size) return;

    int O0 = (N * 64 + 255) / 256;
    int O1 = O0 + (N + 255) / 256;
    int O2 = O1 + 9;
    int O3 = O2 + 228;
    setup_kernel<<<O3, 256, 0, stream>>>(
        x, node_W, node_b, edge_W, edge_b, We, be, Wq, bq, Wk, bk, Wv, bv, Wskip, bskip,
        h, h_bf, counts, Wc, bcb, Wall_arr, Wall_b, O0, O1, O2, N);
    combine2_kernel<<<10, 256, 0, stream>>>(Wq, bq, Wc, bcb, Wall_arr, Wall_b);

    csr_count_kernel<<<(E + 255) / 256, 256, 0, stream>>>(edge_dst, counts, E);
    int nb = (N + 255) / 256;
    scan1_kernel<<<nb, 256, 0, stream>>>(counts, rowptr, bsums, N);
    scan3_kernel<<<nb, 256, 0, stream>>>(rowptr, bsums, cursor, N, E, nb);
    csr_fill_kernel<<<(E + 255) / 256, 256, 0, stream>>>(edge_dst, edge_src, edge_attr,
                                                         cursor, csr_src, ea_perm, E);

    // layer 0
    qkv_mfma_kernel<<<(N + 31) / 32, 256, 0, stream>>>(
        h_bf, Wall_arr, Wall_b, qkv, outbuf, qcbuf, N);
    attn_kernel<<<ATTN_BLOCKS, 256, 0, stream>>>(qkv, qcbuf, csr_src, ea_perm,
                                                 rowptr, Wc, bcb, outbuf, pacc, N);
    bnreduce_kernel<<<128, 256, 0, stream>>>(pacc, bnsums);
    bnqkv_kernel<<<(N + 31) / 32, 256, 0, stream>>>(
        outbuf, bnsums, gamma, beta, h,
        Wall_arr + 32768, Wall_b + 512, qkv, outbuf, qcbuf, N);

    // layer 1
    attn_kernel<<<ATTN_BLOCKS, 256, 0, stream>>>(qkv, qcbuf, csr_src, ea_perm,
                                                 rowptr, Wc + 1024, bcb + 128,
                                                 outbuf, pacc, N);
    bnreduce_kernel<<<128, 256, 0, stream>>>(pacc, bnsums);
    bnapply_kernel<<<(N * 64 + 255) / 256, 256, 0, stream>>>(
        outbuf, bnsums, gamma + 64, beta + 64, gate_W, gate_b, h, gatebuf, N);

    pool_acc_kernel<<<512, 256, 0, stream>>>(h, gatebuf, batch, pacc, pden, N);
    pool_fin_kernel<<<64, 64, 0, stream>>>(pacc, pden, out_W, out_b, out);
}